// Round 7
// baseline (181.486 us; speedup 1.0000x reference)
//
#include <hip/hip_runtime.h>
#include <hip/hip_fp16.h>

#define BB 8
#define NN 8192
#define SS 2048
#define CC 256
#define KNN 8
#define TOPM 10       // per-list candidate count (top-8 + margin 2 for key ties)
#define NLIST 8       // 8 lists per query (4 row-groups x 2 point-halves)
#define QPB 32        // queries per block (16 per wave x 2 query-groups)
#define MSTRIDE 81    // mbuf per-query stride (u32s): 81 mod 32 = 17 -> conflict-free
#define P2STR 66      // prep LDS stride in halves: dword stride 33 (odd) -> conflict-free

#define UMIN(a, b) __builtin_elementwise_min(a, b)
#define UMAX(a, b) __builtin_elementwise_max(a, b)

typedef short bf16x8_t __attribute__((ext_vector_type(8)));   // 8 bf16 = 4 VGPR
typedef float f32x4_t __attribute__((ext_vector_type(4)));

__device__ __forceinline__ float2 unpack_h2(unsigned u) {
    __half2 h = *reinterpret_cast<__half2*>(&u);
    return __half22float2(h);
}

// f32 -> bf16 (RNE) and back, bit-level
__device__ __forceinline__ unsigned short f2bf(float f) {
    unsigned u = __float_as_uint(f);
    u += 0x7FFFu + ((u >> 16) & 1u);
    return (unsigned short)(u >> 16);
}
__device__ __forceinline__ float bf2f(unsigned short h) {
    return __uint_as_float((unsigned)h << 16);
}

// v_med3_u32: for ascending k[j-1]<=k[j]:
// med3(c, k[j-1], k[j]) == min(k[j], max(k[j-1], c)) == sorted-insert update.
__device__ __forceinline__ unsigned med3u(unsigned a, unsigned b, unsigned c) {
    unsigned d;
    asm("v_med3_u32 %0, %1, %2, %3" : "=v"(d) : "v"(a), "v"(b), "v"(c));
    return d;
}

// insert one candidate into ascending top-10: 9 independent med3 + 1 min
__device__ __forceinline__ void ins1(unsigned k1[TOPM], unsigned c) {
#pragma unroll
    for (int j = TOPM - 1; j >= 1; --j)
        k1[j] = med3u(c, k1[j - 1], k1[j]);
    k1[0] = UMIN(k1[0], c);
}

__device__ __forceinline__ void ins_step(unsigned k1[TOPM], f32x4_t d, unsigned sbase) {
    // key = truncated distance bits | point index (11 bits); d > 0 guaranteed (bias)
    ins1(k1, (__float_as_uint(d[0]) & 0xFFFFF800u) | sbase);
    ins1(k1, (__float_as_uint(d[1]) & 0xFFFFF800u) | (sbase + 1u));
    ins1(k1, (__float_as_uint(d[2]) & 0xFFFFF800u) | (sbase + 2u));
    ins1(k1, (__float_as_uint(d[3]) & 0xFFFFF800u) | (sbase + 3u));
}

// ---------------- Kernel P: fused prep (unchanged from round 6) -------------
// Blocks 0..1023:  64s x 64c tile transpose sf [B,C,S] f32 -> sfT [B,S,C] f16.
// Blocks 1024..1087: build split-bf16 MFMA A-tiles gt [B][2][SS][8].
__global__ __launch_bounds__(256) void prep_kernel(
    const float* __restrict__ sf,          // [B,C,S]
    const float* __restrict__ sxyz,        // [B,3,S]
    unsigned short* __restrict__ sft,      // [B][S][C] f16
    unsigned short* __restrict__ gt)       // [B][2][SS][8]
{
    __shared__ unsigned short ts[64 * P2STR];   // 8.25 KB

    const int blk = blockIdx.x;
    const int t   = threadIdx.x;

    if (blk < BB * 32 * 4) {
        const int b  = blk >> 7;
        const int st = (blk >> 2) & 31;
        const int c0 = (blk & 3) * 64;

        const int s  = t & 63;
        const int cq = t >> 6;
        const float* sfb = sf + ((long)b * CC + c0) * SS + st * 64;
#pragma unroll
        for (int it = 0; it < 16; ++it) {
            int c = it * 4 + cq;
            float v = sfb[(long)c * SS + s];                 // 256B/wave coalesced
            ts[s * P2STR + c] = __half_as_ushort(__float2half_rn(v));
        }
        __syncthreads();

        const int so = t >> 2;
        const int cl = t & 3;
        const unsigned short* src = &ts[so * P2STR + cl * 16];
        unsigned u[8];
#pragma unroll
        for (int i = 0; i < 8; ++i) u[i] = *(const unsigned*)&src[i * 2];
        unsigned short* dst = sft + ((long)b * SS + st * 64 + so) * CC + c0 + cl * 16;
        *(uint4*)&dst[0] = make_uint4(u[0], u[1], u[2], u[3]);
        *(uint4*)&dst[8] = make_uint4(u[4], u[5], u[6], u[7]);
    } else {
        const int idx = blk - BB * 32 * 4;
        const int b = idx >> 3;
        const int s = (idx & 7) * 256 + t;
        const float* sb = sxyz + (long)b * 3 * SS;
        unsigned short* gb = gt + (long)b * 2 * SS * 8;

        float px = sb[s], py = sb[SS + s], pz = sb[2 * SS + s];
        unsigned short xh = f2bf(px); unsigned short xl = f2bf(px - bf2f(xh));
        unsigned short yh = f2bf(py); unsigned short yl = f2bf(py - bf2f(yh));
        unsigned short zh = f2bf(pz); unsigned short zl = f2bf(pz - bf2f(zh));
        float pn = fmaf(px, px, fmaf(py, py, pz * pz));
        unsigned short nh = f2bf(pn); unsigned short nl = f2bf(pn - bf2f(nh));
        const unsigned ONE = 0x3F80u;
        // k0..7  = [xh, xl, xh, yh, yl, yh, zh, zl]
        uint4 t0 = make_uint4((unsigned)xh | ((unsigned)xl << 16),
                              (unsigned)xh | ((unsigned)yh << 16),
                              (unsigned)yl | ((unsigned)yh << 16),
                              (unsigned)zh | ((unsigned)zl << 16));
        // k8..15 = [zh, nh, nl, 1, 1, 0, 0, 0]
        uint4 t1 = make_uint4((unsigned)zh | ((unsigned)nh << 16),
                              (unsigned)nl | (ONE << 16),
                              ONE, 0u);
        *(uint4*)&gb[(long)s * 8] = t0;
        *(uint4*)&gb[((long)SS + s) * 8] = t1;
    }
}

// ---------------- Kernel A: MFMA KNN + fused IDW feature accumulation -------
// QPB=32, S split into halves per wave-pair -> grid 2048 = 8 blocks/CU,
// 8 waves/SIMD (2x TLP vs round 6). Wave (wq,wh): 16 queries x 1024 points.
// 8 lists/query; phase 2 re-ranks 80 candidates; phase 3 = 8 threads/query.
__global__ __launch_bounds__(256, 8) void knn_kernel(
    const float* __restrict__ xyz,         // [B,3,N]
    const float* __restrict__ sxyz,        // [B,3,S]
    const unsigned short* __restrict__ gt, // [B][2][SS][8] split-bf16 tiles
    const unsigned short* __restrict__ sft,// [B][S][C] f16 features
    float* __restrict__ out)               // [B,C,N]
{
    __shared__ unsigned mbuf[QPB * MSTRIDE];          // 10.1 KB
    __shared__ unsigned pk_lds[QPB * KNN];            // 1 KB

    const int b    = blockIdx.x >> 8;                 // 256 blocks per batch
    const int q0   = (blockIdx.x & 255) * QPB;
    const int tid  = threadIdx.x;
    const int wave = tid >> 6;
    const int lane = tid & 63;
    const int g    = lane >> 4;                       // MFMA row group
    const int qi   = lane & 15;                       // query-in-group / A-row
    const int wq   = wave & 1;                        // query sub-group
    const int wh   = wave >> 1;                       // point half

    const float* sb = sxyz + (long)b * 3 * SS;
    const float* xb = xyz + (long)b * 3 * NN;

    // ---- per-lane query B-fragment (col = lane&15, k = 8*g + e) ------------
    const int nq = q0 + wq * 16 + qi;
    const float qx = xb[nq], qy = xb[NN + nq], qz = xb[2 * NN + nq];

    bf16x8_t qf = (bf16x8_t)0;
    {
        unsigned short xh = f2bf(qx); float xhf = bf2f(xh);
        unsigned short yh = f2bf(qy); float yhf = bf2f(yh);
        unsigned short zh = f2bf(qz); float zhf = bf2f(zh);
        unsigned short xh2 = f2bf(-2.f * xhf), xl2 = f2bf(-2.f * (qx - xhf));
        unsigned short yh2 = f2bf(-2.f * yhf), yl2 = f2bf(-2.f * (qy - yhf));
        unsigned short zh2 = f2bf(-2.f * zhf), zl2 = f2bf(-2.f * (qz - zhf));
        float qn = fmaf(qx, qx, fmaf(qy, qy, qz * qz)) + 0.0625f;  // bias keeps d>0
        unsigned short nh = f2bf(qn); unsigned short nl = f2bf(qn - bf2f(nh));
        const short ONE = (short)0x3F80;
        if (g == 0) {
            qf[0] = (short)xh2; qf[1] = (short)xh2; qf[2] = (short)xl2;
            qf[3] = (short)yh2; qf[4] = (short)yh2; qf[5] = (short)yl2;
            qf[6] = (short)zh2; qf[7] = (short)zh2;
        } else if (g == 1) {
            qf[0] = (short)zl2; qf[1] = ONE; qf[2] = ONE;
            qf[3] = (short)nh;  qf[4] = (short)nl;
        } // g>=2: zero fragment (k16..31 unused -> A-slices don't matter)
    }

    // ---- phase 1: 64 MFMA steps over this wave's 1024-pt half --------------
    const unsigned short* ap =
        gt + (long)b * 2 * SS * 8 + (long)(g & 1) * SS * 8 + (long)wh * 1024 * 8 + qi * 8;

    unsigned k1[TOPM];
#pragma unroll
    for (int j = 0; j < TOPM; ++j) k1[j] = 0xFFFFFFFFu;

    const f32x4_t zacc = {0.f, 0.f, 0.f, 0.f};
    const unsigned ib = (unsigned)(g * 4 + wh * 1024);

    bf16x8_t a0 = *(const bf16x8_t*)ap; ap += 128;
    bf16x8_t a1 = *(const bf16x8_t*)ap; ap += 128;

    for (int step = 0; step < 62; step += 2) {
        f32x4_t d0 = __builtin_amdgcn_mfma_f32_16x16x32_bf16(a0, qf, zacc, 0, 0, 0);
        a0 = *(const bf16x8_t*)ap; ap += 128;        // load for step+2
        ins_step(k1, d0, ib + (unsigned)(step * 16));
        f32x4_t d1 = __builtin_amdgcn_mfma_f32_16x16x32_bf16(a1, qf, zacc, 0, 0, 0);
        a1 = *(const bf16x8_t*)ap; ap += 128;        // load for step+3
        ins_step(k1, d1, ib + (unsigned)((step + 1) * 16));
    }
    {
        f32x4_t d0 = __builtin_amdgcn_mfma_f32_16x16x32_bf16(a0, qf, zacc, 0, 0, 0);
        ins_step(k1, d0, ib + (unsigned)(62 * 16));
        f32x4_t d1 = __builtin_amdgcn_mfma_f32_16x16x32_bf16(a1, qf, zacc, 0, 0, 0);
        ins_step(k1, d1, ib + (unsigned)(63 * 16));
    }

    {
        // list L = wh*4 + g; row = wq*16 + qi
        unsigned* m1 = &mbuf[(wq * 16 + qi) * MSTRIDE + (wh * 4 + g) * TOPM];
#pragma unroll
        for (int j = 0; j < TOPM; ++j) m1[j] = k1[j];
    }
    __syncthreads();

    // ---- phase 2: one thread per query, f64 re-rank of 80 candidates ------
    if (tid < QPB) {
        const int n2 = q0 + tid;
        const double dqx = (double)xb[n2], dqy = (double)xb[NN + n2], dqz = (double)xb[2 * NN + n2];
        const unsigned* ml = &mbuf[tid * MSTRIDE];

        unsigned long long top[KNN];
#pragma unroll
        for (int j = 0; j < KNN; ++j) top[j] = ~0ull;

#pragma unroll 4
        for (int j = 0; j < NLIST * TOPM; ++j) {
            unsigned key = ml[j];
            int s = key & 0x7FF;
            float px = sb[s], py = sb[SS + s], pz = sb[2 * SS + s];  // L2-hot
            double ex = (double)px - dqx;
            double ey = (double)py - dqy;
            double ez = (double)pz - dqz;
            double dd = ex * ex + ey * ey + ez * ez;
            unsigned long long c =
                (((unsigned long long)__double_as_longlong(dd)) & ~0x7FFull) | (unsigned long long)s;
#pragma unroll
            for (int jj = KNN - 1; jj >= 1; --jj)
                top[jj] = UMIN(UMAX(top[jj - 1], c), top[jj]);
            top[0] = UMIN(top[0], c);
        }

        // IDW weights (f32 math, f16-rounded weight as before)
        const float fqx = xb[n2], fqy = xb[NN + n2], fqz = xb[2 * NN + n2];
        int   id[KNN];
        float inv[KNN];
        float ssum = 0.f;
#pragma unroll
        for (int k = 0; k < KNN; ++k) {
            id[k] = (int)(top[k] & 0x7FFull);
            float px = sb[id[k]], py = sb[SS + id[k]], pz = sb[2 * SS + id[k]];
            float dx = px - fqx, dy = py - fqy, dz = pz - fqz;
            float dv = sqrtf(dx * dx + dy * dy + dz * dz);
            dv = fmaxf(dv, 1e-10f);
            inv[k] = 1.0f / dv;
            ssum += inv[k];
        }
        const float rs = 1.0f / ssum;
#pragma unroll
        for (int k = 0; k < KNN; ++k) {
            unsigned hw = (unsigned)__half_as_ushort(__float2half_rn(inv[k] * rs));
            pk_lds[tid * KNN + k] = (hw << 16) | (unsigned)id[k];
        }
    }
    __syncthreads();

    // ---- phase 3 (fused accum): thread = (query q, channel-lane cl 0..7) ---
    // Per (q,k): 8 cl-lanes read 8x16B = 128B contiguous of sfT[b][id] (L2).
    {
        const int q  = tid >> 3;            // 0..31
        const int cl = tid & 7;             // 0..7
        const unsigned short* sfb = sft + (long)b * SS * CC;
        float* outq = out + (long)b * CC * NN + (q0 + q);

        unsigned pks[KNN];
#pragma unroll
        for (int k = 0; k < KNN; ++k) pks[k] = pk_lds[q * KNN + k];  // LDS broadcast

#pragma unroll
        for (int cc = 0; cc < 4; ++cc) {
            const int ch = cc * 64 + cl * 8;
            float acc[8];
#pragma unroll
            for (int j = 0; j < 8; ++j) acc[j] = 0.f;

#pragma unroll
            for (int k = 0; k < KNN; ++k) {
                const unsigned p = pks[k];
                const int idp = p & 0x7FF;
                const float w = __half2float(__ushort_as_half((unsigned short)(p >> 16)));
                const uint4 F = *(const uint4*)&sfb[(long)idp * CC + ch];  // 16B = 8 ch
                float2 f0 = unpack_h2(F.x), f1 = unpack_h2(F.y);
                float2 f2 = unpack_h2(F.z), f3 = unpack_h2(F.w);
                acc[0] = fmaf(w, f0.x, acc[0]);
                acc[1] = fmaf(w, f0.y, acc[1]);
                acc[2] = fmaf(w, f1.x, acc[2]);
                acc[3] = fmaf(w, f1.y, acc[3]);
                acc[4] = fmaf(w, f2.x, acc[4]);
                acc[5] = fmaf(w, f2.y, acc[5]);
                acc[6] = fmaf(w, f3.x, acc[6]);
                acc[7] = fmaf(w, f3.y, acc[7]);
            }
#pragma unroll
            for (int j = 0; j < 8; ++j)
                outq[(long)(ch + j) * NN] = acc[j];
        }
    }
}

extern "C" void kernel_launch(void* const* d_in, const int* in_sizes, int n_in,
                              void* d_out, int out_size, void* d_ws, size_t ws_size,
                              hipStream_t stream) {
    const float* xyz  = (const float*)d_in[0];   // [8,3,8192]
    const float* sxyz = (const float*)d_in[1];   // [8,3,2048]
    const float* sf   = (const float*)d_in[2];   // [8,256,2048]
    float* out = (float*)d_out;                  // [8,256,8192]

    unsigned short* gtile = (unsigned short*)d_ws;                        // 512 KB
    unsigned short* sft   = (unsigned short*)((char*)d_ws + 512 * 1024);  // 8 MB

    prep_kernel<<<dim3(BB * 32 * 4 + 64), dim3(256), 0, stream>>>(sf, sxyz, sft, gtile);
    knn_kernel<<<dim3(BB * NN / QPB), dim3(256), 0, stream>>>(xyz, sxyz, gtile, sft, out);
}

// Round 8
// 170.631 us; speedup vs baseline: 1.0636x; 1.0636x over previous
//
#include <hip/hip_runtime.h>
#include <hip/hip_fp16.h>

#define BB 8
#define NN 8192
#define SS 2048
#define CC 256
#define KNN 8
#define TOPM 10       // per-list candidate count (top-8 + margin 2 for key ties)
#define NLIST 8       // 8 lists per query (4 row-groups x 2 point-halves)
#define QPB 64        // queries per block (2x16 per wave x 2 query-pair-groups)
#define MSTRIDE 81    // mbuf per-query stride (u32s): odd -> conflict-free
#define P2STR 66      // prep LDS stride in halves: dword stride 33 (odd) -> conflict-free

#define UMIN(a, b) __builtin_elementwise_min(a, b)
#define UMAX(a, b) __builtin_elementwise_max(a, b)

typedef short bf16x8_t __attribute__((ext_vector_type(8)));   // 8 bf16 = 4 VGPR
typedef float f32x4_t __attribute__((ext_vector_type(4)));

__device__ __forceinline__ float2 unpack_h2(unsigned u) {
    __half2 h = *reinterpret_cast<__half2*>(&u);
    return __half22float2(h);
}

// f32 -> bf16 (RNE) and back, bit-level
__device__ __forceinline__ unsigned short f2bf(float f) {
    unsigned u = __float_as_uint(f);
    u += 0x7FFFu + ((u >> 16) & 1u);
    return (unsigned short)(u >> 16);
}
__device__ __forceinline__ float bf2f(unsigned short h) {
    return __uint_as_float((unsigned)h << 16);
}

// v_med3_u32: for ascending k[j-1]<=k[j]:
// med3(c, k[j-1], k[j]) == min(k[j], max(k[j-1], c)) == sorted-insert update.
__device__ __forceinline__ unsigned med3u(unsigned a, unsigned b, unsigned c) {
    unsigned d;
    asm("v_med3_u32 %0, %1, %2, %3" : "=v"(d) : "v"(a), "v"(b), "v"(c));
    return d;
}

// insert one candidate into ascending top-10: 9 independent med3 + 1 min
__device__ __forceinline__ void ins1(unsigned k1[TOPM], unsigned c) {
#pragma unroll
    for (int j = TOPM - 1; j >= 1; --j)
        k1[j] = med3u(c, k1[j - 1], k1[j]);
    k1[0] = UMIN(k1[0], c);
}

__device__ __forceinline__ void ins_step(unsigned k1[TOPM], f32x4_t d, unsigned sbase) {
    // key = truncated distance bits | point index (11 bits); d > 0 guaranteed (bias)
    ins1(k1, (__float_as_uint(d[0]) & 0xFFFFF800u) | sbase);
    ins1(k1, (__float_as_uint(d[1]) & 0xFFFFF800u) | (sbase + 1u));
    ins1(k1, (__float_as_uint(d[2]) & 0xFFFFF800u) | (sbase + 2u));
    ins1(k1, (__float_as_uint(d[3]) & 0xFFFFF800u) | (sbase + 3u));
}

// build the split-bf16 query B-fragment for query index n (k = 8*g + e)
__device__ __forceinline__ bf16x8_t make_qf(const float* xb, int n, int g) {
    const float qx = xb[n], qy = xb[NN + n], qz = xb[2 * NN + n];
    bf16x8_t qf = (bf16x8_t)0;
    unsigned short xh = f2bf(qx); float xhf = bf2f(xh);
    unsigned short yh = f2bf(qy); float yhf = bf2f(yh);
    unsigned short zh = f2bf(qz); float zhf = bf2f(zh);
    unsigned short xh2 = f2bf(-2.f * xhf), xl2 = f2bf(-2.f * (qx - xhf));
    unsigned short yh2 = f2bf(-2.f * yhf), yl2 = f2bf(-2.f * (qy - yhf));
    unsigned short zh2 = f2bf(-2.f * zhf), zl2 = f2bf(-2.f * (qz - zhf));
    float qn = fmaf(qx, qx, fmaf(qy, qy, qz * qz)) + 0.0625f;  // bias keeps d>0
    unsigned short nh = f2bf(qn); unsigned short nl = f2bf(qn - bf2f(nh));
    const short ONE = (short)0x3F80;
    if (g == 0) {
        qf[0] = (short)xh2; qf[1] = (short)xh2; qf[2] = (short)xl2;
        qf[3] = (short)yh2; qf[4] = (short)yh2; qf[5] = (short)yl2;
        qf[6] = (short)zh2; qf[7] = (short)zh2;
    } else if (g == 1) {
        qf[0] = (short)zl2; qf[1] = ONE; qf[2] = ONE;
        qf[3] = (short)nh;  qf[4] = (short)nl;
    } // g>=2: zero fragment (k16..31 unused -> A-slices don't matter)
    return qf;
}

// ---------------- Kernel P: fused prep (unchanged) --------------------------
// Blocks 0..1023:  64s x 64c tile transpose sf [B,C,S] f32 -> sfT [B,S,C] f16.
// Blocks 1024..1087: build split-bf16 MFMA A-tiles gt [B][2][SS][8].
__global__ __launch_bounds__(256) void prep_kernel(
    const float* __restrict__ sf,          // [B,C,S]
    const float* __restrict__ sxyz,        // [B,3,S]
    unsigned short* __restrict__ sft,      // [B][S][C] f16
    unsigned short* __restrict__ gt)       // [B][2][SS][8]
{
    __shared__ unsigned short ts[64 * P2STR];   // 8.25 KB

    const int blk = blockIdx.x;
    const int t   = threadIdx.x;

    if (blk < BB * 32 * 4) {
        const int b  = blk >> 7;
        const int st = (blk >> 2) & 31;
        const int c0 = (blk & 3) * 64;

        const int s  = t & 63;
        const int cq = t >> 6;
        const float* sfb = sf + ((long)b * CC + c0) * SS + st * 64;
#pragma unroll
        for (int it = 0; it < 16; ++it) {
            int c = it * 4 + cq;
            float v = sfb[(long)c * SS + s];                 // 256B/wave coalesced
            ts[s * P2STR + c] = __half_as_ushort(__float2half_rn(v));
        }
        __syncthreads();

        const int so = t >> 2;
        const int cl = t & 3;
        const unsigned short* src = &ts[so * P2STR + cl * 16];
        unsigned u[8];
#pragma unroll
        for (int i = 0; i < 8; ++i) u[i] = *(const unsigned*)&src[i * 2];
        unsigned short* dst = sft + ((long)b * SS + st * 64 + so) * CC + c0 + cl * 16;
        *(uint4*)&dst[0] = make_uint4(u[0], u[1], u[2], u[3]);
        *(uint4*)&dst[8] = make_uint4(u[4], u[5], u[6], u[7]);
    } else {
        const int idx = blk - BB * 32 * 4;
        const int b = idx >> 3;
        const int s = (idx & 7) * 256 + t;
        const float* sb = sxyz + (long)b * 3 * SS;
        unsigned short* gb = gt + (long)b * 2 * SS * 8;

        float px = sb[s], py = sb[SS + s], pz = sb[2 * SS + s];
        unsigned short xh = f2bf(px); unsigned short xl = f2bf(px - bf2f(xh));
        unsigned short yh = f2bf(py); unsigned short yl = f2bf(py - bf2f(yh));
        unsigned short zh = f2bf(pz); unsigned short zl = f2bf(pz - bf2f(zh));
        float pn = fmaf(px, px, fmaf(py, py, pz * pz));
        unsigned short nh = f2bf(pn); unsigned short nl = f2bf(pn - bf2f(nh));
        const unsigned ONE = 0x3F80u;
        // k0..7  = [xh, xl, xh, yh, yl, yh, zh, zl]
        uint4 t0 = make_uint4((unsigned)xh | ((unsigned)xl << 16),
                              (unsigned)xh | ((unsigned)yh << 16),
                              (unsigned)yl | ((unsigned)yh << 16),
                              (unsigned)zh | ((unsigned)zl << 16));
        // k8..15 = [zh, nh, nl, 1, 1, 0, 0, 0]
        uint4 t1 = make_uint4((unsigned)zh | ((unsigned)nh << 16),
                              (unsigned)nl | (ONE << 16),
                              ONE, 0u);
        *(uint4*)&gb[(long)s * 8] = t0;
        *(uint4*)&gb[((long)SS + s) * 8] = t1;
    }
}

// ---------------- Kernel A: MFMA KNN + fused IDW feature accumulation -------
// Wave = (query-pair-group p, point-half h): 32 queries (qfA: cols for queries
// p*32+qi, qfB: p*32+16+qi) x 1024 points, 64 steps. Per step ONE A-load feeds
// TWO MFMAs + two insert-nets -> half the VMEM per candidate vs round 6.
__global__ __launch_bounds__(256, 4) void knn_kernel(
    const float* __restrict__ xyz,         // [B,3,N]
    const float* __restrict__ sxyz,        // [B,3,S]
    const unsigned short* __restrict__ gt, // [B][2][SS][8] split-bf16 tiles
    const unsigned short* __restrict__ sft,// [B][S][C] f16 features
    float* __restrict__ out)               // [B,C,N]
{
    __shared__ unsigned mbuf[QPB * MSTRIDE];          // 20.25 KB
    __shared__ unsigned pk_lds[QPB * KNN];            // 2 KB

    const int b    = blockIdx.x >> 7;                 // 128 blocks per batch
    const int q0   = (blockIdx.x & 127) * QPB;
    const int tid  = threadIdx.x;
    const int wave = tid >> 6;
    const int lane = tid & 63;
    const int g    = lane >> 4;                       // MFMA row group
    const int qi   = lane & 15;                       // query col / A row
    const int p    = wave & 1;                        // query pair-group
    const int h    = wave >> 1;                       // point half

    const float* sb = sxyz + (long)b * 3 * SS;
    const float* xb = xyz + (long)b * 3 * NN;

    // ---- two per-lane query B-fragments ------------------------------------
    const int nqA = q0 + p * 32 + qi;
    const bf16x8_t qfA = make_qf(xb, nqA, g);
    const bf16x8_t qfB = make_qf(xb, nqA + 16, g);

    // ---- phase 1: 64 steps over this wave's 1024-pt half, 2 MFMAs/load -----
    const unsigned short* ap =
        gt + (long)b * 2 * SS * 8 + (long)(g & 1) * SS * 8 + (long)h * 1024 * 8 + qi * 8;

    unsigned k1A[TOPM], k1B[TOPM];
#pragma unroll
    for (int j = 0; j < TOPM; ++j) { k1A[j] = 0xFFFFFFFFu; k1B[j] = 0xFFFFFFFFu; }

    const f32x4_t zacc = {0.f, 0.f, 0.f, 0.f};
    const unsigned ib = (unsigned)(g * 4 + h * 1024);

    bf16x8_t a0 = *(const bf16x8_t*)ap; ap += 128;
    bf16x8_t a1 = *(const bf16x8_t*)ap; ap += 128;

    for (int step = 0; step < 62; step += 2) {
        f32x4_t d0 = __builtin_amdgcn_mfma_f32_16x16x32_bf16(a0, qfA, zacc, 0, 0, 0);
        f32x4_t e0 = __builtin_amdgcn_mfma_f32_16x16x32_bf16(a0, qfB, zacc, 0, 0, 0);
        a0 = *(const bf16x8_t*)ap; ap += 128;        // load for step+2
        ins_step(k1A, d0, ib + (unsigned)(step * 16));
        ins_step(k1B, e0, ib + (unsigned)(step * 16));
        f32x4_t d1 = __builtin_amdgcn_mfma_f32_16x16x32_bf16(a1, qfA, zacc, 0, 0, 0);
        f32x4_t e1 = __builtin_amdgcn_mfma_f32_16x16x32_bf16(a1, qfB, zacc, 0, 0, 0);
        a1 = *(const bf16x8_t*)ap; ap += 128;        // load for step+3
        ins_step(k1A, d1, ib + (unsigned)((step + 1) * 16));
        ins_step(k1B, e1, ib + (unsigned)((step + 1) * 16));
    }
    {
        f32x4_t d0 = __builtin_amdgcn_mfma_f32_16x16x32_bf16(a0, qfA, zacc, 0, 0, 0);
        f32x4_t e0 = __builtin_amdgcn_mfma_f32_16x16x32_bf16(a0, qfB, zacc, 0, 0, 0);
        ins_step(k1A, d0, ib + (unsigned)(62 * 16));
        ins_step(k1B, e0, ib + (unsigned)(62 * 16));
        f32x4_t d1 = __builtin_amdgcn_mfma_f32_16x16x32_bf16(a1, qfA, zacc, 0, 0, 0);
        f32x4_t e1 = __builtin_amdgcn_mfma_f32_16x16x32_bf16(a1, qfB, zacc, 0, 0, 0);
        ins_step(k1A, d1, ib + (unsigned)(63 * 16));
        ins_step(k1B, e1, ib + (unsigned)(63 * 16));
    }

    {
        // list L = h*4 + g; rows p*32+qi (set A) and p*32+16+qi (set B)
        unsigned* mA = &mbuf[(p * 32 + qi) * MSTRIDE + (h * 4 + g) * TOPM];
        unsigned* mB = &mbuf[(p * 32 + 16 + qi) * MSTRIDE + (h * 4 + g) * TOPM];
#pragma unroll
        for (int j = 0; j < TOPM; ++j) { mA[j] = k1A[j]; mB[j] = k1B[j]; }
    }
    __syncthreads();

    // ---- phase 2: one thread per query, f64 re-rank of 80 candidates ------
    if (tid < QPB) {
        const int n2 = q0 + tid;
        const double dqx = (double)xb[n2], dqy = (double)xb[NN + n2], dqz = (double)xb[2 * NN + n2];
        const unsigned* ml = &mbuf[tid * MSTRIDE];

        unsigned long long top[KNN];
#pragma unroll
        for (int j = 0; j < KNN; ++j) top[j] = ~0ull;

#pragma unroll 4
        for (int j = 0; j < NLIST * TOPM; ++j) {
            unsigned key = ml[j];
            int s = key & 0x7FF;
            float px = sb[s], py = sb[SS + s], pz = sb[2 * SS + s];  // L2-hot
            double ex = (double)px - dqx;
            double ey = (double)py - dqy;
            double ez = (double)pz - dqz;
            double dd = ex * ex + ey * ey + ez * ez;
            unsigned long long c =
                (((unsigned long long)__double_as_longlong(dd)) & ~0x7FFull) | (unsigned long long)s;
#pragma unroll
            for (int jj = KNN - 1; jj >= 1; --jj)
                top[jj] = UMIN(UMAX(top[jj - 1], c), top[jj]);
            top[0] = UMIN(top[0], c);
        }

        // IDW weights (f32 math, f16-rounded weight as before)
        const float fqx = xb[n2], fqy = xb[NN + n2], fqz = xb[2 * NN + n2];
        int   id[KNN];
        float inv[KNN];
        float ssum = 0.f;
#pragma unroll
        for (int k = 0; k < KNN; ++k) {
            id[k] = (int)(top[k] & 0x7FFull);
            float px = sb[id[k]], py = sb[SS + id[k]], pz = sb[2 * SS + id[k]];
            float dx = px - fqx, dy = py - fqy, dz = pz - fqz;
            float dv = sqrtf(dx * dx + dy * dy + dz * dz);
            dv = fmaxf(dv, 1e-10f);
            inv[k] = 1.0f / dv;
            ssum += inv[k];
        }
        const float rs = 1.0f / ssum;
#pragma unroll
        for (int k = 0; k < KNN; ++k) {
            unsigned hw = (unsigned)__half_as_ushort(__float2half_rn(inv[k] * rs));
            pk_lds[tid * KNN + k] = (hw << 16) | (unsigned)id[k];
        }
    }
    __syncthreads();

    // ---- phase 3 (fused accum): thread = (query q, channel-lane cl) --------
    {
        const int q  = tid >> 2;
        const int cl = tid & 3;
        const unsigned short* sfb = sft + (long)b * SS * CC;
        float* outq = out + (long)b * CC * NN + (q0 + q);

        unsigned pks[KNN];
#pragma unroll
        for (int k = 0; k < KNN; ++k) pks[k] = pk_lds[q * KNN + k];  // LDS broadcast

#pragma unroll
        for (int cc = 0; cc < 8; ++cc) {
            const int ch = cc * 32 + cl * 8;
            float acc[8];
#pragma unroll
            for (int j = 0; j < 8; ++j) acc[j] = 0.f;

#pragma unroll
            for (int k = 0; k < KNN; ++k) {
                const unsigned p2 = pks[k];
                const int idp = p2 & 0x7FF;
                const float w = __half2float(__ushort_as_half((unsigned short)(p2 >> 16)));
                const uint4 F = *(const uint4*)&sfb[(long)idp * CC + ch];  // 16B = 8 ch
                float2 f0 = unpack_h2(F.x), f1 = unpack_h2(F.y);
                float2 f2 = unpack_h2(F.z), f3 = unpack_h2(F.w);
                acc[0] = fmaf(w, f0.x, acc[0]);
                acc[1] = fmaf(w, f0.y, acc[1]);
                acc[2] = fmaf(w, f1.x, acc[2]);
                acc[3] = fmaf(w, f1.y, acc[3]);
                acc[4] = fmaf(w, f2.x, acc[4]);
                acc[5] = fmaf(w, f2.y, acc[5]);
                acc[6] = fmaf(w, f3.x, acc[6]);
                acc[7] = fmaf(w, f3.y, acc[7]);
            }
#pragma unroll
            for (int j = 0; j < 8; ++j)
                outq[(long)(ch + j) * NN] = acc[j];
        }
    }
}

extern "C" void kernel_launch(void* const* d_in, const int* in_sizes, int n_in,
                              void* d_out, int out_size, void* d_ws, size_t ws_size,
                              hipStream_t stream) {
    const float* xyz  = (const float*)d_in[0];   // [8,3,8192]
    const float* sxyz = (const float*)d_in[1];   // [8,3,2048]
    const float* sf   = (const float*)d_in[2];   // [8,256,2048]
    float* out = (float*)d_out;                  // [8,256,8192]

    unsigned short* gtile = (unsigned short*)d_ws;                        // 512 KB
    unsigned short* sft   = (unsigned short*)((char*)d_ws + 512 * 1024);  // 8 MB

    prep_kernel<<<dim3(BB * 32 * 4 + 64), dim3(256), 0, stream>>>(sf, sxyz, sft, gtile);
    knn_kernel<<<dim3(BB * NN / QPB), dim3(256), 0, stream>>>(xyz, sxyz, gtile, sft, out);
}

// Round 9
// 156.792 us; speedup vs baseline: 1.1575x; 1.0883x over previous
//
#include <hip/hip_runtime.h>
#include <hip/hip_fp16.h>

#define BB 8
#define NN 8192
#define SS 2048
#define CC 256
#define KNN 8
#define TOPM 10       // per-list candidate count (top-8 + margin 2 for key ties)
#define NLIST 4       // 4 lists per query (one per 16-lane MFMA row group)
#define QPB 64        // queries per block (16 per wave x 4 waves)
#define MSTRIDE 41    // mbuf per-query stride (u32s): 41 mod 32 = 9 -> conflict-free
#define P2STR 66      // prep LDS stride in halves: dword stride 33 (odd) -> conflict-free

#define UMIN(a, b) __builtin_elementwise_min(a, b)
#define UMAX(a, b) __builtin_elementwise_max(a, b)

typedef short bf16x8_t __attribute__((ext_vector_type(8)));   // 8 bf16 = 4 VGPR
typedef float f32x4_t __attribute__((ext_vector_type(4)));

__device__ __forceinline__ float2 unpack_h2(unsigned u) {
    __half2 h = *reinterpret_cast<__half2*>(&u);
    return __half22float2(h);
}

// f32 -> bf16 (RNE) and back, bit-level
__device__ __forceinline__ unsigned short f2bf(float f) {
    unsigned u = __float_as_uint(f);
    u += 0x7FFFu + ((u >> 16) & 1u);
    return (unsigned short)(u >> 16);
}
__device__ __forceinline__ float bf2f(unsigned short h) {
    return __uint_as_float((unsigned)h << 16);
}

// v_med3_u32: for ascending k[j-1]<=k[j]:
// med3(c, k[j-1], k[j]) == min(k[j], max(k[j-1], c)) == sorted-insert update.
__device__ __forceinline__ unsigned med3u(unsigned a, unsigned b, unsigned c) {
    unsigned d;
    asm("v_med3_u32 %0, %1, %2, %3" : "=v"(d) : "v"(a), "v"(b), "v"(c));
    return d;
}

// insert one candidate into ascending top-10: 9 independent med3 + 1 min
__device__ __forceinline__ void ins1(unsigned k1[TOPM], unsigned c) {
#pragma unroll
    for (int j = TOPM - 1; j >= 1; --j)
        k1[j] = med3u(c, k1[j - 1], k1[j]);
    k1[0] = UMIN(k1[0], c);
}

__device__ __forceinline__ void ins_step(unsigned k1[TOPM], f32x4_t d, unsigned sbase) {
    // key = truncated distance bits | point index (11 bits); d > 0 guaranteed (bias)
    ins1(k1, (__float_as_uint(d[0]) & 0xFFFFF800u) | sbase);
    ins1(k1, (__float_as_uint(d[1]) & 0xFFFFF800u) | (sbase + 1u));
    ins1(k1, (__float_as_uint(d[2]) & 0xFFFFF800u) | (sbase + 2u));
    ins1(k1, (__float_as_uint(d[3]) & 0xFFFFF800u) | (sbase + 3u));
}

// ---------------- Kernel P: fused prep ---------------------------------------
// Blocks 0..1023:  64s x 64c tile transpose sf [B,C,S] f32 -> sfT [B,S,C] f16.
// Blocks 1024..1087: build split-bf16 MFMA A-tiles gt [B][2][SS][8].
// t1 now carries xl,yl,zl at k13..15 (ql*pl cross terms -> ~3x accuracy).
__global__ __launch_bounds__(256) void prep_kernel(
    const float* __restrict__ sf,          // [B,C,S]
    const float* __restrict__ sxyz,        // [B,3,S]
    unsigned short* __restrict__ sft,      // [B][S][C] f16
    unsigned short* __restrict__ gt)       // [B][2][SS][8]
{
    __shared__ unsigned short ts[64 * P2STR];   // 8.25 KB

    const int blk = blockIdx.x;
    const int t   = threadIdx.x;

    if (blk < BB * 32 * 4) {
        const int b  = blk >> 7;
        const int st = (blk >> 2) & 31;
        const int c0 = (blk & 3) * 64;

        const int s  = t & 63;
        const int cq = t >> 6;
        const float* sfb = sf + ((long)b * CC + c0) * SS + st * 64;
#pragma unroll
        for (int it = 0; it < 16; ++it) {
            int c = it * 4 + cq;
            float v = sfb[(long)c * SS + s];                 // 256B/wave coalesced
            ts[s * P2STR + c] = __half_as_ushort(__float2half_rn(v));
        }
        __syncthreads();

        const int so = t >> 2;
        const int cl = t & 3;
        const unsigned short* src = &ts[so * P2STR + cl * 16];
        unsigned u[8];
#pragma unroll
        for (int i = 0; i < 8; ++i) u[i] = *(const unsigned*)&src[i * 2];
        unsigned short* dst = sft + ((long)b * SS + st * 64 + so) * CC + c0 + cl * 16;
        *(uint4*)&dst[0] = make_uint4(u[0], u[1], u[2], u[3]);
        *(uint4*)&dst[8] = make_uint4(u[4], u[5], u[6], u[7]);
    } else {
        const int idx = blk - BB * 32 * 4;
        const int b = idx >> 3;
        const int s = (idx & 7) * 256 + t;
        const float* sb = sxyz + (long)b * 3 * SS;
        unsigned short* gb = gt + (long)b * 2 * SS * 8;

        float px = sb[s], py = sb[SS + s], pz = sb[2 * SS + s];
        unsigned short xh = f2bf(px); unsigned short xl = f2bf(px - bf2f(xh));
        unsigned short yh = f2bf(py); unsigned short yl = f2bf(py - bf2f(yh));
        unsigned short zh = f2bf(pz); unsigned short zl = f2bf(pz - bf2f(zh));
        float pn = fmaf(px, px, fmaf(py, py, pz * pz));
        unsigned short nh = f2bf(pn); unsigned short nl = f2bf(pn - bf2f(nh));
        const unsigned ONE = 0x3F80u;
        // k0..7  = [xh, xl, xh, yh, yl, yh, zh, zl]
        uint4 t0 = make_uint4((unsigned)xh | ((unsigned)xl << 16),
                              (unsigned)xh | ((unsigned)yh << 16),
                              (unsigned)yl | ((unsigned)yh << 16),
                              (unsigned)zh | ((unsigned)zl << 16));
        // k8..15 = [zh, nh, nl, 1, 1, xl, yl, zl]
        uint4 t1 = make_uint4((unsigned)zh | ((unsigned)nh << 16),
                              (unsigned)nl | (ONE << 16),
                              ONE | ((unsigned)xl << 16),
                              (unsigned)yl | ((unsigned)zl << 16));
        *(uint4*)&gb[(long)s * 8] = t0;
        *(uint4*)&gb[((long)SS + s) * 8] = t1;
    }
}

// ---------------- Kernel A: MFMA KNN + fused IDW feature accumulation -------
// Phase 1: r6 structure (128 MFMA steps, med3 insert, depth-2 prefetch).
// Phase 2: u32 funnel-merge of 4 sorted lists -> top-10, f64 re-rank of 10.
// Phase 3: fused gather with hoisted weight/index decode.
__global__ __launch_bounds__(256, 4) void knn_kernel(
    const float* __restrict__ xyz,         // [B,3,N]
    const float* __restrict__ sxyz,        // [B,3,S]
    const unsigned short* __restrict__ gt, // [B][2][SS][8] split-bf16 tiles
    const unsigned short* __restrict__ sft,// [B][S][C] f16 features
    float* __restrict__ out)               // [B,C,N]
{
    __shared__ unsigned mbuf[QPB * MSTRIDE];          // 10.25 KB
    __shared__ unsigned pk_lds[QPB * KNN];            // 2 KB

    const int b    = blockIdx.x >> 7;                 // 128 blocks per batch
    const int q0   = (blockIdx.x & 127) * QPB;
    const int tid  = threadIdx.x;
    const int wave = tid >> 6;
    const int lane = tid & 63;
    const int g    = lane >> 4;                       // MFMA row group / list id
    const int qi   = lane & 15;                       // query-in-wave / A-row

    const float* sb = sxyz + (long)b * 3 * SS;
    const float* xb = xyz + (long)b * 3 * NN;

    // ---- per-lane query B-fragment (col = lane&15, k = 8*g + e) ------------
    const int nq = q0 + wave * 16 + qi;
    const float qx = xb[nq], qy = xb[NN + nq], qz = xb[2 * NN + nq];

    bf16x8_t qf = (bf16x8_t)0;
    {
        unsigned short xh = f2bf(qx); float xhf = bf2f(xh);
        unsigned short yh = f2bf(qy); float yhf = bf2f(yh);
        unsigned short zh = f2bf(qz); float zhf = bf2f(zh);
        unsigned short xh2 = f2bf(-2.f * xhf), xl2 = f2bf(-2.f * (qx - xhf));
        unsigned short yh2 = f2bf(-2.f * yhf), yl2 = f2bf(-2.f * (qy - yhf));
        unsigned short zh2 = f2bf(-2.f * zhf), zl2 = f2bf(-2.f * (qz - zhf));
        float qn = fmaf(qx, qx, fmaf(qy, qy, qz * qz)) + 0.0625f;  // bias keeps d>0
        unsigned short nh = f2bf(qn); unsigned short nl = f2bf(qn - bf2f(nh));
        const short ONE = (short)0x3F80;
        if (g == 0) {
            qf[0] = (short)xh2; qf[1] = (short)xh2; qf[2] = (short)xl2;
            qf[3] = (short)yh2; qf[4] = (short)yh2; qf[5] = (short)yl2;
            qf[6] = (short)zh2; qf[7] = (short)zh2;
        } else if (g == 1) {
            // k8..15: zl2*zh, |p|2h, |p|2l, |q|2h, |q|2l, xl2*pxl, yl2*pyl, zl2*pzl
            qf[0] = (short)zl2; qf[1] = ONE; qf[2] = ONE;
            qf[3] = (short)nh;  qf[4] = (short)nl;
            qf[5] = (short)xl2; qf[6] = (short)yl2; qf[7] = (short)zl2;
        } // g>=2: zero fragment (k16..31 unused -> A-slices don't matter)
    }

    // ---- phase 1: 128 MFMA steps, prefetch distance 2, med3 insertion ------
    const unsigned short* ap =
        gt + (long)b * 2 * SS * 8 + (long)(g & 1) * SS * 8 + qi * 8;

    unsigned k1[TOPM];
#pragma unroll
    for (int j = 0; j < TOPM; ++j) k1[j] = 0xFFFFFFFFu;

    const f32x4_t zacc = {0.f, 0.f, 0.f, 0.f};
    const unsigned ib4 = (unsigned)(g * 4);

    bf16x8_t a0 = *(const bf16x8_t*)ap; ap += 128;
    bf16x8_t a1 = *(const bf16x8_t*)ap; ap += 128;

    for (int step = 0; step < 126; step += 2) {
        f32x4_t d0 = __builtin_amdgcn_mfma_f32_16x16x32_bf16(a0, qf, zacc, 0, 0, 0);
        a0 = *(const bf16x8_t*)ap; ap += 128;        // load for step+2
        ins_step(k1, d0, ib4 + (unsigned)(step * 16));
        f32x4_t d1 = __builtin_amdgcn_mfma_f32_16x16x32_bf16(a1, qf, zacc, 0, 0, 0);
        a1 = *(const bf16x8_t*)ap; ap += 128;        // load for step+3
        ins_step(k1, d1, ib4 + (unsigned)((step + 1) * 16));
    }
    {
        f32x4_t d0 = __builtin_amdgcn_mfma_f32_16x16x32_bf16(a0, qf, zacc, 0, 0, 0);
        ins_step(k1, d0, ib4 + (unsigned)(126 * 16));
        f32x4_t d1 = __builtin_amdgcn_mfma_f32_16x16x32_bf16(a1, qf, zacc, 0, 0, 0);
        ins_step(k1, d1, ib4 + (unsigned)(127 * 16));
    }

    {
        unsigned* m1 = &mbuf[(wave * 16 + qi) * MSTRIDE + g * TOPM];
#pragma unroll
        for (int j = 0; j < TOPM; ++j) m1[j] = k1[j];
    }
    __syncthreads();

    // ---- phase 2: u32 funnel (40 -> top-10) + f64 re-rank of 10 ------------
    if (tid < QPB) {
        const int n2 = q0 + tid;
        const unsigned* ml = &mbuf[tid * MSTRIDE];

        // cheap u32 merge of the 4 approx lists (med3 insert, 40 x 10 ops)
        unsigned f1[TOPM];
#pragma unroll
        for (int j = 0; j < TOPM; ++j) f1[j] = 0xFFFFFFFFu;
#pragma unroll 4
        for (int j = 0; j < NLIST * TOPM; ++j) ins1(f1, ml[j]);

        // exact f64 distances for the surviving 10, insert into top-8 u64
        const double dqx = (double)xb[n2], dqy = (double)xb[NN + n2], dqz = (double)xb[2 * NN + n2];
        unsigned long long top[KNN];
#pragma unroll
        for (int j = 0; j < KNN; ++j) top[j] = ~0ull;

#pragma unroll
        for (int j = 0; j < TOPM; ++j) {
            int s = f1[j] & 0x7FF;
            float px = sb[s], py = sb[SS + s], pz = sb[2 * SS + s];  // L2-hot
            double ex = (double)px - dqx;
            double ey = (double)py - dqy;
            double ez = (double)pz - dqz;
            double dd = ex * ex + ey * ey + ez * ez;
            unsigned long long c =
                (((unsigned long long)__double_as_longlong(dd)) & ~0x7FFull) | (unsigned long long)s;
#pragma unroll
            for (int jj = KNN - 1; jj >= 1; --jj)
                top[jj] = UMIN(UMAX(top[jj - 1], c), top[jj]);
            top[0] = UMIN(top[0], c);
        }

        // IDW weights (f32 math, f16-rounded weight as before)
        const float fqx = xb[n2], fqy = xb[NN + n2], fqz = xb[2 * NN + n2];
        int   id[KNN];
        float inv[KNN];
        float ssum = 0.f;
#pragma unroll
        for (int k = 0; k < KNN; ++k) {
            id[k] = (int)(top[k] & 0x7FFull);
            float px = sb[id[k]], py = sb[SS + id[k]], pz = sb[2 * SS + id[k]];
            float dx = px - fqx, dy = py - fqy, dz = pz - fqz;
            float dv = sqrtf(dx * dx + dy * dy + dz * dz);
            dv = fmaxf(dv, 1e-10f);
            inv[k] = 1.0f / dv;
            ssum += inv[k];
        }
        const float rs = 1.0f / ssum;
#pragma unroll
        for (int k = 0; k < KNN; ++k) {
            unsigned hw = (unsigned)__half_as_ushort(__float2half_rn(inv[k] * rs));
            pk_lds[tid * KNN + k] = (hw << 16) | (unsigned)id[k];
        }
    }
    __syncthreads();

    // ---- phase 3 (fused accum): thread = (query q, channel-lane cl) --------
    {
        const int q  = tid >> 2;
        const int cl = tid & 3;
        const unsigned short* sfb = sft + (long)b * SS * CC;
        float* outq = out + (long)b * CC * NN + (q0 + q);

        // hoisted decode: weights + row offsets once per thread
        float wgt[KNN];
        long  off[KNN];
#pragma unroll
        for (int k = 0; k < KNN; ++k) {
            const unsigned p = pk_lds[q * KNN + k];           // LDS broadcast
            off[k] = (long)(p & 0x7FF) * CC;
            wgt[k] = __half2float(__ushort_as_half((unsigned short)(p >> 16)));
        }

#pragma unroll
        for (int cc = 0; cc < 8; ++cc) {
            const int ch = cc * 32 + cl * 8;
            float acc[8];
#pragma unroll
            for (int j = 0; j < 8; ++j) acc[j] = 0.f;

#pragma unroll
            for (int k = 0; k < KNN; ++k) {
                const float w = wgt[k];
                const uint4 F = *(const uint4*)&sfb[off[k] + ch];  // 16B = 8 ch
                float2 f0 = unpack_h2(F.x), f1 = unpack_h2(F.y);
                float2 f2 = unpack_h2(F.z), f3 = unpack_h2(F.w);
                acc[0] = fmaf(w, f0.x, acc[0]);
                acc[1] = fmaf(w, f0.y, acc[1]);
                acc[2] = fmaf(w, f1.x, acc[2]);
                acc[3] = fmaf(w, f1.y, acc[3]);
                acc[4] = fmaf(w, f2.x, acc[4]);
                acc[5] = fmaf(w, f2.y, acc[5]);
                acc[6] = fmaf(w, f3.x, acc[6]);
                acc[7] = fmaf(w, f3.y, acc[7]);
            }
#pragma unroll
            for (int j = 0; j < 8; ++j)
                outq[(long)(ch + j) * NN] = acc[j];
        }
    }
}

extern "C" void kernel_launch(void* const* d_in, const int* in_sizes, int n_in,
                              void* d_out, int out_size, void* d_ws, size_t ws_size,
                              hipStream_t stream) {
    const float* xyz  = (const float*)d_in[0];   // [8,3,8192]
    const float* sxyz = (const float*)d_in[1];   // [8,3,2048]
    const float* sf   = (const float*)d_in[2];   // [8,256,2048]
    float* out = (float*)d_out;                  // [8,256,8192]

    unsigned short* gtile = (unsigned short*)d_ws;                        // 512 KB
    unsigned short* sft   = (unsigned short*)((char*)d_ws + 512 * 1024);  // 8 MB

    prep_kernel<<<dim3(BB * 32 * 4 + 64), dim3(256), 0, stream>>>(sf, sxyz, sft, gtile);
    knn_kernel<<<dim3(BB * NN / QPB), dim3(256), 0, stream>>>(xyz, sxyz, gtile, sft, out);
}

// Round 10
// 153.707 us; speedup vs baseline: 1.1807x; 1.0201x over previous
//
#include <hip/hip_runtime.h>
#include <hip/hip_fp16.h>

#define BB 8
#define NN 8192
#define SS 2048
#define CC 256
#define KNN 8
#define TOPM 10       // per-list candidate count (top-8 + margin 2 for key ties)
#define NLIST 4       // 4 lists per query (one per 16-lane MFMA row group)
#define QPB 64        // queries per block (16 per wave x 4 waves)
#define MSTRIDE 41    // mbuf per-query stride (u32s): 41 mod 32 = 9 -> conflict-free
#define P2STR 66      // prep LDS stride in halves: dword stride 33 (odd) -> conflict-free

#define UMIN(a, b) __builtin_elementwise_min(a, b)
#define UMAX(a, b) __builtin_elementwise_max(a, b)

typedef short bf16x8_t __attribute__((ext_vector_type(8)));   // 8 bf16 = 4 VGPR
typedef float f32x4_t __attribute__((ext_vector_type(4)));

__device__ __forceinline__ float2 unpack_h2(unsigned u) {
    __half2 h = *reinterpret_cast<__half2*>(&u);
    return __half22float2(h);
}

// f32 -> bf16 (RNE) and back, bit-level
__device__ __forceinline__ unsigned short f2bf(float f) {
    unsigned u = __float_as_uint(f);
    u += 0x7FFFu + ((u >> 16) & 1u);
    return (unsigned short)(u >> 16);
}
__device__ __forceinline__ float bf2f(unsigned short h) {
    return __uint_as_float((unsigned)h << 16);
}

// v_med3_u32: for ascending k[j-1]<=k[j]:
// med3(c, k[j-1], k[j]) == min(k[j], max(k[j-1], c)) == sorted-insert update.
__device__ __forceinline__ unsigned med3u(unsigned a, unsigned b, unsigned c) {
    unsigned d;
    asm("v_med3_u32 %0, %1, %2, %3" : "=v"(d) : "v"(a), "v"(b), "v"(c));
    return d;
}

// insert one candidate into ascending top-10: 9 independent med3 + 1 min
__device__ __forceinline__ void ins1(unsigned k1[TOPM], unsigned c) {
#pragma unroll
    for (int j = TOPM - 1; j >= 1; --j)
        k1[j] = med3u(c, k1[j - 1], k1[j]);
    k1[0] = UMIN(k1[0], c);
}

__device__ __forceinline__ void ins_step(unsigned k1[TOPM], f32x4_t d, unsigned sbase) {
    // key = truncated distance bits | point index (11 bits); d > 0 guaranteed (bias)
    ins1(k1, (__float_as_uint(d[0]) & 0xFFFFF800u) | sbase);
    ins1(k1, (__float_as_uint(d[1]) & 0xFFFFF800u) | (sbase + 1u));
    ins1(k1, (__float_as_uint(d[2]) & 0xFFFFF800u) | (sbase + 2u));
    ins1(k1, (__float_as_uint(d[3]) & 0xFFFFF800u) | (sbase + 3u));
}

// ---------------- Kernel P: fused prep (XCD-affine: batch = blk & 7) --------
// Blocks 0..1023:  64s x 64c tile transpose sf [B,C,S] f32 -> sfT [B,S,C] f16.
// Blocks 1024..1087: build split-bf16 MFMA A-tiles gt [B][2][SS][8].
__global__ __launch_bounds__(256) void prep_kernel(
    const float* __restrict__ sf,          // [B,C,S]
    const float* __restrict__ sxyz,        // [B,3,S]
    unsigned short* __restrict__ sft,      // [B][S][C] f16
    unsigned short* __restrict__ gt)       // [B][2][SS][8]
{
    __shared__ unsigned short ts[64 * P2STR];   // 8.25 KB

    const int blk = blockIdx.x;
    const int t   = threadIdx.x;

    if (blk < BB * 32 * 4) {
        // XCD-affinity: batch = blk & 7 (round-robin dispatch -> one batch/XCD)
        const int b  = blk & 7;
        const int r  = blk >> 3;          // 0..127
        const int st = r & 31;            // s-tile
        const int c0 = (r >> 5) * 64;     // channel tile

        const int s  = t & 63;
        const int cq = t >> 6;
        const float* sfb = sf + ((long)b * CC + c0) * SS + st * 64;
#pragma unroll
        for (int it = 0; it < 16; ++it) {
            int c = it * 4 + cq;
            float v = sfb[(long)c * SS + s];                 // 256B/wave coalesced
            ts[s * P2STR + c] = __half_as_ushort(__float2half_rn(v));
        }
        __syncthreads();

        const int so = t >> 2;
        const int cl = t & 3;
        const unsigned short* src = &ts[so * P2STR + cl * 16];
        unsigned u[8];
#pragma unroll
        for (int i = 0; i < 8; ++i) u[i] = *(const unsigned*)&src[i * 2];
        unsigned short* dst = sft + ((long)b * SS + st * 64 + so) * CC + c0 + cl * 16;
        *(uint4*)&dst[0] = make_uint4(u[0], u[1], u[2], u[3]);
        *(uint4*)&dst[8] = make_uint4(u[4], u[5], u[6], u[7]);
    } else {
        const int idx = blk - BB * 32 * 4;
        const int b = idx & 7;            // XCD-affine
        const int s = (idx >> 3) * 256 + t;
        const float* sb = sxyz + (long)b * 3 * SS;
        unsigned short* gb = gt + (long)b * 2 * SS * 8;

        float px = sb[s], py = sb[SS + s], pz = sb[2 * SS + s];
        unsigned short xh = f2bf(px); unsigned short xl = f2bf(px - bf2f(xh));
        unsigned short yh = f2bf(py); unsigned short yl = f2bf(py - bf2f(yh));
        unsigned short zh = f2bf(pz); unsigned short zl = f2bf(pz - bf2f(zh));
        float pn = fmaf(px, px, fmaf(py, py, pz * pz));
        unsigned short nh = f2bf(pn); unsigned short nl = f2bf(pn - bf2f(nh));
        const unsigned ONE = 0x3F80u;
        // k0..7  = [xh, xl, xh, yh, yl, yh, zh, zl]
        uint4 t0 = make_uint4((unsigned)xh | ((unsigned)xl << 16),
                              (unsigned)xh | ((unsigned)yh << 16),
                              (unsigned)yl | ((unsigned)yh << 16),
                              (unsigned)zh | ((unsigned)zl << 16));
        // k8..15 = [zh, nh, nl, 1, 1, xl, yl, zl]
        uint4 t1 = make_uint4((unsigned)zh | ((unsigned)nh << 16),
                              (unsigned)nl | (ONE << 16),
                              ONE | ((unsigned)xl << 16),
                              (unsigned)yl | ((unsigned)zl << 16));
        *(uint4*)&gb[(long)s * 8] = t0;
        *(uint4*)&gb[((long)SS + s) * 8] = t1;
    }
}

// ---------------- Kernel A: MFMA KNN + fused IDW feature accumulation -------
// XCD-affine: batch = blockIdx & 7 -> per-XCD working set (gt 512K + sfT 1M +
// xyz 96K) fits the 4MB L2; phase-1 loads become L2 hits inside prefetch slack.
// out stores are non-temporal so the 8MB/batch stream doesn't evict gt/sfT.
__global__ __launch_bounds__(256, 4) void knn_kernel(
    const float* __restrict__ xyz,         // [B,3,N]
    const float* __restrict__ sxyz,        // [B,3,S]
    const unsigned short* __restrict__ gt, // [B][2][SS][8] split-bf16 tiles
    const unsigned short* __restrict__ sft,// [B][S][C] f16 features
    float* __restrict__ out)               // [B,C,N]
{
    __shared__ unsigned mbuf[QPB * MSTRIDE];          // 10.25 KB
    __shared__ unsigned pk_lds[QPB * KNN];            // 2 KB

    const int b    = blockIdx.x & 7;                  // XCD-affine batch
    const int q0   = (int)(blockIdx.x >> 3) * QPB;    // 128 q-groups per batch
    const int tid  = threadIdx.x;
    const int wave = tid >> 6;
    const int lane = tid & 63;
    const int g    = lane >> 4;                       // MFMA row group / list id
    const int qi   = lane & 15;                       // query-in-wave / A-row

    const float* sb = sxyz + (long)b * 3 * SS;
    const float* xb = xyz + (long)b * 3 * NN;

    // ---- per-lane query B-fragment (col = lane&15, k = 8*g + e) ------------
    const int nq = q0 + wave * 16 + qi;
    const float qx = xb[nq], qy = xb[NN + nq], qz = xb[2 * NN + nq];

    bf16x8_t qf = (bf16x8_t)0;
    {
        unsigned short xh = f2bf(qx); float xhf = bf2f(xh);
        unsigned short yh = f2bf(qy); float yhf = bf2f(yh);
        unsigned short zh = f2bf(qz); float zhf = bf2f(zh);
        unsigned short xh2 = f2bf(-2.f * xhf), xl2 = f2bf(-2.f * (qx - xhf));
        unsigned short yh2 = f2bf(-2.f * yhf), yl2 = f2bf(-2.f * (qy - yhf));
        unsigned short zh2 = f2bf(-2.f * zhf), zl2 = f2bf(-2.f * (qz - zhf));
        float qn = fmaf(qx, qx, fmaf(qy, qy, qz * qz)) + 0.0625f;  // bias keeps d>0
        unsigned short nh = f2bf(qn); unsigned short nl = f2bf(qn - bf2f(nh));
        const short ONE = (short)0x3F80;
        if (g == 0) {
            qf[0] = (short)xh2; qf[1] = (short)xh2; qf[2] = (short)xl2;
            qf[3] = (short)yh2; qf[4] = (short)yh2; qf[5] = (short)yl2;
            qf[6] = (short)zh2; qf[7] = (short)zh2;
        } else if (g == 1) {
            // k8..15: zl2*zh, |p|2h, |p|2l, |q|2h, |q|2l, xl2*pxl, yl2*pyl, zl2*pzl
            qf[0] = (short)zl2; qf[1] = ONE; qf[2] = ONE;
            qf[3] = (short)nh;  qf[4] = (short)nl;
            qf[5] = (short)xl2; qf[6] = (short)yl2; qf[7] = (short)zl2;
        } // g>=2: zero fragment (k16..31 unused -> A-slices don't matter)
    }

    // ---- phase 1: 128 MFMA steps, prefetch distance 2, med3 insertion ------
    const unsigned short* ap =
        gt + (long)b * 2 * SS * 8 + (long)(g & 1) * SS * 8 + qi * 8;

    unsigned k1[TOPM];
#pragma unroll
    for (int j = 0; j < TOPM; ++j) k1[j] = 0xFFFFFFFFu;

    const f32x4_t zacc = {0.f, 0.f, 0.f, 0.f};
    const unsigned ib4 = (unsigned)(g * 4);

    bf16x8_t a0 = *(const bf16x8_t*)ap; ap += 128;
    bf16x8_t a1 = *(const bf16x8_t*)ap; ap += 128;

    for (int step = 0; step < 126; step += 2) {
        f32x4_t d0 = __builtin_amdgcn_mfma_f32_16x16x32_bf16(a0, qf, zacc, 0, 0, 0);
        a0 = *(const bf16x8_t*)ap; ap += 128;        // load for step+2
        ins_step(k1, d0, ib4 + (unsigned)(step * 16));
        f32x4_t d1 = __builtin_amdgcn_mfma_f32_16x16x32_bf16(a1, qf, zacc, 0, 0, 0);
        a1 = *(const bf16x8_t*)ap; ap += 128;        // load for step+3
        ins_step(k1, d1, ib4 + (unsigned)((step + 1) * 16));
    }
    {
        f32x4_t d0 = __builtin_amdgcn_mfma_f32_16x16x32_bf16(a0, qf, zacc, 0, 0, 0);
        ins_step(k1, d0, ib4 + (unsigned)(126 * 16));
        f32x4_t d1 = __builtin_amdgcn_mfma_f32_16x16x32_bf16(a1, qf, zacc, 0, 0, 0);
        ins_step(k1, d1, ib4 + (unsigned)(127 * 16));
    }

    {
        unsigned* m1 = &mbuf[(wave * 16 + qi) * MSTRIDE + g * TOPM];
#pragma unroll
        for (int j = 0; j < TOPM; ++j) m1[j] = k1[j];
    }
    __syncthreads();

    // ---- phase 2: u32 funnel (40 -> top-10) + f64 re-rank of 10 ------------
    if (tid < QPB) {
        const int n2 = q0 + tid;
        const unsigned* ml = &mbuf[tid * MSTRIDE];

        // cheap u32 merge of the 4 approx lists (med3 insert, 40 x 10 ops)
        unsigned f1[TOPM];
#pragma unroll
        for (int j = 0; j < TOPM; ++j) f1[j] = 0xFFFFFFFFu;
#pragma unroll 4
        for (int j = 0; j < NLIST * TOPM; ++j) ins1(f1, ml[j]);

        // exact f64 distances for the surviving 10, insert into top-8 u64
        const double dqx = (double)xb[n2], dqy = (double)xb[NN + n2], dqz = (double)xb[2 * NN + n2];
        unsigned long long top[KNN];
#pragma unroll
        for (int j = 0; j < KNN; ++j) top[j] = ~0ull;

#pragma unroll
        for (int j = 0; j < TOPM; ++j) {
            int s = f1[j] & 0x7FF;
            float px = sb[s], py = sb[SS + s], pz = sb[2 * SS + s];  // L2-hot
            double ex = (double)px - dqx;
            double ey = (double)py - dqy;
            double ez = (double)pz - dqz;
            double dd = ex * ex + ey * ey + ez * ez;
            unsigned long long c =
                (((unsigned long long)__double_as_longlong(dd)) & ~0x7FFull) | (unsigned long long)s;
#pragma unroll
            for (int jj = KNN - 1; jj >= 1; --jj)
                top[jj] = UMIN(UMAX(top[jj - 1], c), top[jj]);
            top[0] = UMIN(top[0], c);
        }

        // IDW weights (f32 math, f16-rounded weight as before)
        const float fqx = xb[n2], fqy = xb[NN + n2], fqz = xb[2 * NN + n2];
        int   id[KNN];
        float inv[KNN];
        float ssum = 0.f;
#pragma unroll
        for (int k = 0; k < KNN; ++k) {
            id[k] = (int)(top[k] & 0x7FFull);
            float px = sb[id[k]], py = sb[SS + id[k]], pz = sb[2 * SS + id[k]];
            float dx = px - fqx, dy = py - fqy, dz = pz - fqz;
            float dv = sqrtf(dx * dx + dy * dy + dz * dz);
            dv = fmaxf(dv, 1e-10f);
            inv[k] = 1.0f / dv;
            ssum += inv[k];
        }
        const float rs = 1.0f / ssum;
#pragma unroll
        for (int k = 0; k < KNN; ++k) {
            unsigned hw = (unsigned)__half_as_ushort(__float2half_rn(inv[k] * rs));
            pk_lds[tid * KNN + k] = (hw << 16) | (unsigned)id[k];
        }
    }
    __syncthreads();

    // ---- phase 3 (fused accum): thread = (query q, channel-lane cl) --------
    {
        const int q  = tid >> 2;
        const int cl = tid & 3;
        const unsigned short* sfb = sft + (long)b * SS * CC;
        float* outq = out + (long)b * CC * NN + (q0 + q);

        // hoisted decode: weights + row offsets once per thread
        float wgt[KNN];
        long  off[KNN];
#pragma unroll
        for (int k = 0; k < KNN; ++k) {
            const unsigned p = pk_lds[q * KNN + k];           // LDS broadcast
            off[k] = (long)(p & 0x7FF) * CC;
            wgt[k] = __half2float(__ushort_as_half((unsigned short)(p >> 16)));
        }

#pragma unroll
        for (int cc = 0; cc < 8; ++cc) {
            const int ch = cc * 32 + cl * 8;
            float acc[8];
#pragma unroll
            for (int j = 0; j < 8; ++j) acc[j] = 0.f;

#pragma unroll
            for (int k = 0; k < KNN; ++k) {
                const float w = wgt[k];
                const uint4 F = *(const uint4*)&sfb[off[k] + ch];  // 16B = 8 ch (L2-hit)
                float2 f0 = unpack_h2(F.x), f1 = unpack_h2(F.y);
                float2 f2 = unpack_h2(F.z), f3 = unpack_h2(F.w);
                acc[0] = fmaf(w, f0.x, acc[0]);
                acc[1] = fmaf(w, f0.y, acc[1]);
                acc[2] = fmaf(w, f1.x, acc[2]);
                acc[3] = fmaf(w, f1.y, acc[3]);
                acc[4] = fmaf(w, f2.x, acc[4]);
                acc[5] = fmaf(w, f2.y, acc[5]);
                acc[6] = fmaf(w, f3.x, acc[6]);
                acc[7] = fmaf(w, f3.y, acc[7]);
            }
#pragma unroll
            for (int j = 0; j < 8; ++j)
                __builtin_nontemporal_store(acc[j], &outq[(long)(ch + j) * NN]);
        }
    }
}

extern "C" void kernel_launch(void* const* d_in, const int* in_sizes, int n_in,
                              void* d_out, int out_size, void* d_ws, size_t ws_size,
                              hipStream_t stream) {
    const float* xyz  = (const float*)d_in[0];   // [8,3,8192]
    const float* sxyz = (const float*)d_in[1];   // [8,3,2048]
    const float* sf   = (const float*)d_in[2];   // [8,256,2048]
    float* out = (float*)d_out;                  // [8,256,8192]

    unsigned short* gtile = (unsigned short*)d_ws;                        // 512 KB
    unsigned short* sft   = (unsigned short*)((char*)d_ws + 512 * 1024);  // 8 MB

    prep_kernel<<<dim3(BB * 32 * 4 + 64), dim3(256), 0, stream>>>(sf, sxyz, sft, gtile);
    knn_kernel<<<dim3(BB * NN / QPB), dim3(256), 0, stream>>>(xyz, sxyz, gtile, sft, out);
}

// Round 11
// 152.281 us; speedup vs baseline: 1.1918x; 1.0094x over previous
//
#include <hip/hip_runtime.h>
#include <hip/hip_fp16.h>

#define BB 8
#define NN 8192
#define SS 2048
#define CC 256
#define KNN 8
#define TOPM 10       // per-list candidate count (top-8 + margin 2 for key ties)
#define NLIST 4       // 4 lists per query (one per 16-lane MFMA row group)
#define QPB 64        // queries per block (16 per wave x 4 waves)
#define MSTRIDE 41    // mbuf per-query stride (u32s): 41 mod 32 = 9 -> conflict-free
#define P2STR 66      // prep LDS stride in halves: dword stride 33 (odd) -> conflict-free

#define UMIN(a, b) __builtin_elementwise_min(a, b)
#define UMAX(a, b) __builtin_elementwise_max(a, b)

typedef short bf16x8_t __attribute__((ext_vector_type(8)));   // 8 bf16 = 4 VGPR
typedef float f32x4_t __attribute__((ext_vector_type(4)));

__device__ __forceinline__ float2 unpack_h2(unsigned u) {
    __half2 h = *reinterpret_cast<__half2*>(&u);
    return __half22float2(h);
}

// f32 -> bf16 (RNE) and back, bit-level
__device__ __forceinline__ unsigned short f2bf(float f) {
    unsigned u = __float_as_uint(f);
    u += 0x7FFFu + ((u >> 16) & 1u);
    return (unsigned short)(u >> 16);
}
__device__ __forceinline__ float bf2f(unsigned short h) {
    return __uint_as_float((unsigned)h << 16);
}

// v_med3_u32: for ascending k[j-1]<=k[j]:
// med3(c, k[j-1], k[j]) == min(k[j], max(k[j-1], c)) == sorted-insert update.
__device__ __forceinline__ unsigned med3u(unsigned a, unsigned b, unsigned c) {
    unsigned d;
    asm("v_med3_u32 %0, %1, %2, %3" : "=v"(d) : "v"(a), "v"(b), "v"(c));
    return d;
}

// insert one candidate into ascending top-10: 9 independent med3 + 1 min
__device__ __forceinline__ void ins1(unsigned k1[TOPM], unsigned c) {
#pragma unroll
    for (int j = TOPM - 1; j >= 1; --j)
        k1[j] = med3u(c, k1[j - 1], k1[j]);
    k1[0] = UMIN(k1[0], c);
}

__device__ __forceinline__ void ins_step(unsigned k1[TOPM], f32x4_t d, unsigned sbase) {
    // key = truncated distance bits | point index (11 bits); d > 0 guaranteed (bias)
    ins1(k1, (__float_as_uint(d[0]) & 0xFFFFF800u) | sbase);
    ins1(k1, (__float_as_uint(d[1]) & 0xFFFFF800u) | (sbase + 1u));
    ins1(k1, (__float_as_uint(d[2]) & 0xFFFFF800u) | (sbase + 2u));
    ins1(k1, (__float_as_uint(d[3]) & 0xFFFFF800u) | (sbase + 3u));
}

// ---------------- Kernel P: fused prep (XCD-affine: batch = blk & 7) --------
// Blocks 0..1023:  64s x 64c tile transpose sf [B,C,S] f32 -> sfT [B,S,C] f16.
// Blocks 1024..1087: build split-bf16 MFMA A-tiles gt [B][2][SS][8].
__global__ __launch_bounds__(256) void prep_kernel(
    const float* __restrict__ sf,          // [B,C,S]
    const float* __restrict__ sxyz,        // [B,3,S]
    unsigned short* __restrict__ sft,      // [B][S][C] f16
    unsigned short* __restrict__ gt)       // [B][2][SS][8]
{
    __shared__ unsigned short ts[64 * P2STR];   // 8.25 KB

    const int blk = blockIdx.x;
    const int t   = threadIdx.x;

    if (blk < BB * 32 * 4) {
        // XCD-affinity: batch = blk & 7 (round-robin dispatch -> one batch/XCD)
        const int b  = blk & 7;
        const int r  = blk >> 3;          // 0..127
        const int st = r & 31;            // s-tile
        const int c0 = (r >> 5) * 64;     // channel tile

        const int s  = t & 63;
        const int cq = t >> 6;
        const float* sfb = sf + ((long)b * CC + c0) * SS + st * 64;
#pragma unroll
        for (int it = 0; it < 16; ++it) {
            int c = it * 4 + cq;
            float v = sfb[(long)c * SS + s];                 // 256B/wave coalesced
            ts[s * P2STR + c] = __half_as_ushort(__float2half_rn(v));
        }
        __syncthreads();

        const int so = t >> 2;
        const int cl = t & 3;
        const unsigned short* src = &ts[so * P2STR + cl * 16];
        unsigned u[8];
#pragma unroll
        for (int i = 0; i < 8; ++i) u[i] = *(const unsigned*)&src[i * 2];
        unsigned short* dst = sft + ((long)b * SS + st * 64 + so) * CC + c0 + cl * 16;
        *(uint4*)&dst[0] = make_uint4(u[0], u[1], u[2], u[3]);
        *(uint4*)&dst[8] = make_uint4(u[4], u[5], u[6], u[7]);
    } else {
        const int idx = blk - BB * 32 * 4;
        const int b = idx & 7;            // XCD-affine
        const int s = (idx >> 3) * 256 + t;
        const float* sb = sxyz + (long)b * 3 * SS;
        unsigned short* gb = gt + (long)b * 2 * SS * 8;

        float px = sb[s], py = sb[SS + s], pz = sb[2 * SS + s];
        unsigned short xh = f2bf(px); unsigned short xl = f2bf(px - bf2f(xh));
        unsigned short yh = f2bf(py); unsigned short yl = f2bf(py - bf2f(yh));
        unsigned short zh = f2bf(pz); unsigned short zl = f2bf(pz - bf2f(zh));
        float pn = fmaf(px, px, fmaf(py, py, pz * pz));
        unsigned short nh = f2bf(pn); unsigned short nl = f2bf(pn - bf2f(nh));
        const unsigned ONE = 0x3F80u;
        // k0..7  = [xh, xl, xh, yh, yl, yh, zh, zl]
        uint4 t0 = make_uint4((unsigned)xh | ((unsigned)xl << 16),
                              (unsigned)xh | ((unsigned)yh << 16),
                              (unsigned)yl | ((unsigned)yh << 16),
                              (unsigned)zh | ((unsigned)zl << 16));
        // k8..15 = [zh, nh, nl, 1, 1, xl, yl, zl]
        uint4 t1 = make_uint4((unsigned)zh | ((unsigned)nh << 16),
                              (unsigned)nl | (ONE << 16),
                              ONE | ((unsigned)xl << 16),
                              (unsigned)yl | ((unsigned)zl << 16));
        *(uint4*)&gb[(long)s * 8] = t0;
        *(uint4*)&gb[((long)SS + s) * 8] = t1;
    }
}

// ---------------- Kernel A: MFMA KNN + fused IDW feature accumulation -------
// Phase 1: 4-deep buffer, paired-MFMA-then-deferred-insert schedule: every
// MFMA result (except d0) has >=80cy of independent insert work between
// issue and first use; loads run 4 steps (~380cy) ahead of consumption.
__global__ __launch_bounds__(256, 4) void knn_kernel(
    const float* __restrict__ xyz,         // [B,3,N]
    const float* __restrict__ sxyz,        // [B,3,S]
    const unsigned short* __restrict__ gt, // [B][2][SS][8] split-bf16 tiles
    const unsigned short* __restrict__ sft,// [B][S][C] f16 features
    float* __restrict__ out)               // [B,C,N]
{
    __shared__ unsigned mbuf[QPB * MSTRIDE];          // 10.25 KB
    __shared__ unsigned pk_lds[QPB * KNN];            // 2 KB

    const int b    = blockIdx.x & 7;                  // XCD-affine batch
    const int q0   = (int)(blockIdx.x >> 3) * QPB;    // 128 q-groups per batch
    const int tid  = threadIdx.x;
    const int wave = tid >> 6;
    const int lane = tid & 63;
    const int g    = lane >> 4;                       // MFMA row group / list id
    const int qi   = lane & 15;                       // query-in-wave / A-row

    const float* sb = sxyz + (long)b * 3 * SS;
    const float* xb = xyz + (long)b * 3 * NN;

    // ---- per-lane query B-fragment (col = lane&15, k = 8*g + e) ------------
    const int nq = q0 + wave * 16 + qi;
    const float qx = xb[nq], qy = xb[NN + nq], qz = xb[2 * NN + nq];

    bf16x8_t qf = (bf16x8_t)0;
    {
        unsigned short xh = f2bf(qx); float xhf = bf2f(xh);
        unsigned short yh = f2bf(qy); float yhf = bf2f(yh);
        unsigned short zh = f2bf(qz); float zhf = bf2f(zh);
        unsigned short xh2 = f2bf(-2.f * xhf), xl2 = f2bf(-2.f * (qx - xhf));
        unsigned short yh2 = f2bf(-2.f * yhf), yl2 = f2bf(-2.f * (qy - yhf));
        unsigned short zh2 = f2bf(-2.f * zhf), zl2 = f2bf(-2.f * (qz - zhf));
        float qn = fmaf(qx, qx, fmaf(qy, qy, qz * qz)) + 0.0625f;  // bias keeps d>0
        unsigned short nh = f2bf(qn); unsigned short nl = f2bf(qn - bf2f(nh));
        const short ONE = (short)0x3F80;
        if (g == 0) {
            qf[0] = (short)xh2; qf[1] = (short)xh2; qf[2] = (short)xl2;
            qf[3] = (short)yh2; qf[4] = (short)yh2; qf[5] = (short)yl2;
            qf[6] = (short)zh2; qf[7] = (short)zh2;
        } else if (g == 1) {
            // k8..15: zl2*zh, |p|2h, |p|2l, |q|2h, |q|2l, xl2*pxl, yl2*pyl, zl2*pzl
            qf[0] = (short)zl2; qf[1] = ONE; qf[2] = ONE;
            qf[3] = (short)nh;  qf[4] = (short)nl;
            qf[5] = (short)xl2; qf[6] = (short)yl2; qf[7] = (short)zl2;
        } // g>=2: zero fragment (k16..31 unused -> A-slices don't matter)
    }

    // ---- phase 1: 128 MFMA steps, 4-deep buffer, deferred inserts ----------
    const unsigned short* ap =
        gt + (long)b * 2 * SS * 8 + (long)(g & 1) * SS * 8 + qi * 8;

    unsigned k1[TOPM];
#pragma unroll
    for (int j = 0; j < TOPM; ++j) k1[j] = 0xFFFFFFFFu;

    const f32x4_t zacc = {0.f, 0.f, 0.f, 0.f};
    const unsigned ib4 = (unsigned)(g * 4);

    bf16x8_t a0 = *(const bf16x8_t*)(ap);
    bf16x8_t a1 = *(const bf16x8_t*)(ap + 128);
    bf16x8_t a2 = *(const bf16x8_t*)(ap + 256);
    bf16x8_t a3 = *(const bf16x8_t*)(ap + 384);
    ap += 512;

    for (int step = 0; step < 124; step += 4) {
        // pair 0: two MFMAs issued back-to-back, then prefetches, THEN insert
        f32x4_t d0 = __builtin_amdgcn_mfma_f32_16x16x32_bf16(a0, qf, zacc, 0, 0, 0);
        f32x4_t d1 = __builtin_amdgcn_mfma_f32_16x16x32_bf16(a1, qf, zacc, 0, 0, 0);
        a0 = *(const bf16x8_t*)(ap);            // loads for steps +4, +5
        a1 = *(const bf16x8_t*)(ap + 128);
        ins_step(k1, d0, ib4 + (unsigned)(step * 16));          // d1 ages ~80cy
        // pair 1
        f32x4_t d2 = __builtin_amdgcn_mfma_f32_16x16x32_bf16(a2, qf, zacc, 0, 0, 0);
        f32x4_t d3 = __builtin_amdgcn_mfma_f32_16x16x32_bf16(a3, qf, zacc, 0, 0, 0);
        a2 = *(const bf16x8_t*)(ap + 256);      // loads for steps +6, +7
        a3 = *(const bf16x8_t*)(ap + 384);
        ap += 512;
        ins_step(k1, d1, ib4 + (unsigned)((step + 1) * 16));
        ins_step(k1, d2, ib4 + (unsigned)((step + 2) * 16));    // d2 aged ~80cy
        ins_step(k1, d3, ib4 + (unsigned)((step + 3) * 16));    // d3 aged ~160cy
    }
    {   // tail: steps 124..127 (buffers already loaded, no prefetch)
        f32x4_t d0 = __builtin_amdgcn_mfma_f32_16x16x32_bf16(a0, qf, zacc, 0, 0, 0);
        f32x4_t d1 = __builtin_amdgcn_mfma_f32_16x16x32_bf16(a1, qf, zacc, 0, 0, 0);
        ins_step(k1, d0, ib4 + (unsigned)(124 * 16));
        f32x4_t d2 = __builtin_amdgcn_mfma_f32_16x16x32_bf16(a2, qf, zacc, 0, 0, 0);
        f32x4_t d3 = __builtin_amdgcn_mfma_f32_16x16x32_bf16(a3, qf, zacc, 0, 0, 0);
        ins_step(k1, d1, ib4 + (unsigned)(125 * 16));
        ins_step(k1, d2, ib4 + (unsigned)(126 * 16));
        ins_step(k1, d3, ib4 + (unsigned)(127 * 16));
    }

    {
        unsigned* m1 = &mbuf[(wave * 16 + qi) * MSTRIDE + g * TOPM];
#pragma unroll
        for (int j = 0; j < TOPM; ++j) m1[j] = k1[j];
    }
    __syncthreads();

    // ---- phase 2: u32 funnel (40 -> top-10) + f64 re-rank of 10 ------------
    if (tid < QPB) {
        const int n2 = q0 + tid;
        const unsigned* ml = &mbuf[tid * MSTRIDE];

        // cheap u32 merge of the 4 approx lists (med3 insert, 40 x 10 ops)
        unsigned f1[TOPM];
#pragma unroll
        for (int j = 0; j < TOPM; ++j) f1[j] = 0xFFFFFFFFu;
#pragma unroll 4
        for (int j = 0; j < NLIST * TOPM; ++j) ins1(f1, ml[j]);

        // exact f64 distances for the surviving 10, insert into top-8 u64
        const double dqx = (double)xb[n2], dqy = (double)xb[NN + n2], dqz = (double)xb[2 * NN + n2];
        unsigned long long top[KNN];
#pragma unroll
        for (int j = 0; j < KNN; ++j) top[j] = ~0ull;

#pragma unroll
        for (int j = 0; j < TOPM; ++j) {
            int s = f1[j] & 0x7FF;
            float px = sb[s], py = sb[SS + s], pz = sb[2 * SS + s];  // L2-hot
            double ex = (double)px - dqx;
            double ey = (double)py - dqy;
            double ez = (double)pz - dqz;
            double dd = ex * ex + ey * ey + ez * ez;
            unsigned long long c =
                (((unsigned long long)__double_as_longlong(dd)) & ~0x7FFull) | (unsigned long long)s;
#pragma unroll
            for (int jj = KNN - 1; jj >= 1; --jj)
                top[jj] = UMIN(UMAX(top[jj - 1], c), top[jj]);
            top[0] = UMIN(top[0], c);
        }

        // IDW weights (f32 math, f16-rounded weight as before)
        const float fqx = xb[n2], fqy = xb[NN + n2], fqz = xb[2 * NN + n2];
        int   id[KNN];
        float inv[KNN];
        float ssum = 0.f;
#pragma unroll
        for (int k = 0; k < KNN; ++k) {
            id[k] = (int)(top[k] & 0x7FFull);
            float px = sb[id[k]], py = sb[SS + id[k]], pz = sb[2 * SS + id[k]];
            float dx = px - fqx, dy = py - fqy, dz = pz - fqz;
            float dv = sqrtf(dx * dx + dy * dy + dz * dz);
            dv = fmaxf(dv, 1e-10f);
            inv[k] = 1.0f / dv;
            ssum += inv[k];
        }
        const float rs = 1.0f / ssum;
#pragma unroll
        for (int k = 0; k < KNN; ++k) {
            unsigned hw = (unsigned)__half_as_ushort(__float2half_rn(inv[k] * rs));
            pk_lds[tid * KNN + k] = (hw << 16) | (unsigned)id[k];
        }
    }
    __syncthreads();

    // ---- phase 3 (fused accum): thread = (query q, channel-lane cl) --------
    {
        const int q  = tid >> 2;
        const int cl = tid & 3;
        const unsigned short* sfb = sft + (long)b * SS * CC;
        float* outq = out + (long)b * CC * NN + (q0 + q);

        // hoisted decode: weights + row offsets once per thread
        float wgt[KNN];
        long  off[KNN];
#pragma unroll
        for (int k = 0; k < KNN; ++k) {
            const unsigned p = pk_lds[q * KNN + k];           // LDS broadcast
            off[k] = (long)(p & 0x7FF) * CC;
            wgt[k] = __half2float(__ushort_as_half((unsigned short)(p >> 16)));
        }

#pragma unroll
        for (int cc = 0; cc < 8; ++cc) {
            const int ch = cc * 32 + cl * 8;
            float acc[8];
#pragma unroll
            for (int j = 0; j < 8; ++j) acc[j] = 0.f;

#pragma unroll
            for (int k = 0; k < KNN; ++k) {
                const float w = wgt[k];
                const uint4 F = *(const uint4*)&sfb[off[k] + ch];  // 16B = 8 ch (L2-hit)
                float2 f0 = unpack_h2(F.x), f1 = unpack_h2(F.y);
                float2 f2 = unpack_h2(F.z), f3 = unpack_h2(F.w);
                acc[0] = fmaf(w, f0.x, acc[0]);
                acc[1] = fmaf(w, f0.y, acc[1]);
                acc[2] = fmaf(w, f1.x, acc[2]);
                acc[3] = fmaf(w, f1.y, acc[3]);
                acc[4] = fmaf(w, f2.x, acc[4]);
                acc[5] = fmaf(w, f2.y, acc[5]);
                acc[6] = fmaf(w, f3.x, acc[6]);
                acc[7] = fmaf(w, f3.y, acc[7]);
            }
#pragma unroll
            for (int j = 0; j < 8; ++j)
                __builtin_nontemporal_store(acc[j], &outq[(long)(ch + j) * NN]);
        }
    }
}

extern "C" void kernel_launch(void* const* d_in, const int* in_sizes, int n_in,
                              void* d_out, int out_size, void* d_ws, size_t ws_size,
                              hipStream_t stream) {
    const float* xyz  = (const float*)d_in[0];   // [8,3,8192]
    const float* sxyz = (const float*)d_in[1];   // [8,3,2048]
    const float* sf   = (const float*)d_in[2];   // [8,256,2048]
    float* out = (float*)d_out;                  // [8,256,8192]

    unsigned short* gtile = (unsigned short*)d_ws;                        // 512 KB
    unsigned short* sft   = (unsigned short*)((char*)d_ws + 512 * 1024);  // 8 MB

    prep_kernel<<<dim3(BB * 32 * 4 + 64), dim3(256), 0, stream>>>(sf, sxyz, sft, gtile);
    knn_kernel<<<dim3(BB * NN / QPB), dim3(256), 0, stream>>>(xyz, sxyz, gtile, sft, out);
}

// Round 12
// 146.392 us; speedup vs baseline: 1.2397x; 1.0402x over previous
//
#include <hip/hip_runtime.h>
#include <hip/hip_fp16.h>

#define BB 8
#define NN 8192
#define SS 2048
#define CC 256
#define KNN 8
#define TOPM 10       // per-list candidate count (top-8 + margin 2 for key ties)
#define NLIST 4       // 4 lists per query (2 s-half waves x 2 lane-halves)
#define QPB 64        // queries per block (32 per wave-pair x 2 query groups)
#define MSTRIDE 41    // mbuf per-query stride (u32s): 41 mod 32 = 9 -> conflict-free
#define P2STR 66      // prep LDS stride in halves: dword stride 33 (odd) -> conflict-free

#define UMIN(a, b) __builtin_elementwise_min(a, b)
#define UMAX(a, b) __builtin_elementwise_max(a, b)

typedef short bf16x8_t  __attribute__((ext_vector_type(8)));    // 8 bf16 = 4 VGPR
typedef float f32x4_t   __attribute__((ext_vector_type(4)));
typedef float f32x16_t  __attribute__((ext_vector_type(16)));   // 32x32 D frag

__device__ __forceinline__ float2 unpack_h2(unsigned u) {
    __half2 h = *reinterpret_cast<__half2*>(&u);
    return __half22float2(h);
}

// f32 -> bf16 (RNE) and back, bit-level
__device__ __forceinline__ unsigned short f2bf(float f) {
    unsigned u = __float_as_uint(f);
    u += 0x7FFFu + ((u >> 16) & 1u);
    return (unsigned short)(u >> 16);
}
__device__ __forceinline__ float bf2f(unsigned short h) {
    return __uint_as_float((unsigned)h << 16);
}

// v_med3_u32: for ascending k[j-1]<=k[j]:
// med3(c, k[j-1], k[j]) == min(k[j], max(k[j-1], c)) == sorted-insert update.
__device__ __forceinline__ unsigned med3u(unsigned a, unsigned b, unsigned c) {
    unsigned d;
    asm("v_med3_u32 %0, %1, %2, %3" : "=v"(d) : "v"(a), "v"(b), "v"(c));
    return d;
}

// insert one candidate into ascending top-10: 9 independent med3 + 1 min
__device__ __forceinline__ void ins1(unsigned k1[TOPM], unsigned c) {
#pragma unroll
    for (int j = TOPM - 1; j >= 1; --j)
        k1[j] = med3u(c, k1[j - 1], k1[j]);
    k1[0] = UMIN(k1[0], c);
}

// insert all 16 D-fragment rows; idx = sbase + (r&3) + 8*(r>>2)  (4h in sbase)
__device__ __forceinline__ void ins_step16(unsigned k1[TOPM], f32x16_t d, unsigned sbase) {
#pragma unroll
    for (int r = 0; r < 16; ++r) {
        unsigned idx = sbase + (unsigned)((r & 3) + 8 * (r >> 2));
        ins1(k1, (__float_as_uint(d[r]) & 0xFFFFF800u) | idx);
    }
}

// ---------------- Kernel P: fused prep (XCD-affine: batch = blk & 7) --------
// Blocks 0..1023:  64s x 64c tile transpose sf [B,C,S] f32 -> sfT [B,S,C] f16.
// Blocks 1024..1087: build split-bf16 MFMA A-tiles gt [B][2][SS][8].
__global__ __launch_bounds__(256) void prep_kernel(
    const float* __restrict__ sf,          // [B,C,S]
    const float* __restrict__ sxyz,        // [B,3,S]
    unsigned short* __restrict__ sft,      // [B][S][C] f16
    unsigned short* __restrict__ gt)       // [B][2][SS][8]
{
    __shared__ unsigned short ts[64 * P2STR];   // 8.25 KB

    const int blk = blockIdx.x;
    const int t   = threadIdx.x;

    if (blk < BB * 32 * 4) {
        // XCD-affinity: batch = blk & 7 (round-robin dispatch -> one batch/XCD)
        const int b  = blk & 7;
        const int r  = blk >> 3;          // 0..127
        const int st = r & 31;            // s-tile
        const int c0 = (r >> 5) * 64;     // channel tile

        const int s  = t & 63;
        const int cq = t >> 6;
        const float* sfb = sf + ((long)b * CC + c0) * SS + st * 64;
#pragma unroll
        for (int it = 0; it < 16; ++it) {
            int c = it * 4 + cq;
            float v = sfb[(long)c * SS + s];                 // 256B/wave coalesced
            ts[s * P2STR + c] = __half_as_ushort(__float2half_rn(v));
        }
        __syncthreads();

        const int so = t >> 2;
        const int cl = t & 3;
        const unsigned short* src = &ts[so * P2STR + cl * 16];
        unsigned u[8];
#pragma unroll
        for (int i = 0; i < 8; ++i) u[i] = *(const unsigned*)&src[i * 2];
        unsigned short* dst = sft + ((long)b * SS + st * 64 + so) * CC + c0 + cl * 16;
        *(uint4*)&dst[0] = make_uint4(u[0], u[1], u[2], u[3]);
        *(uint4*)&dst[8] = make_uint4(u[4], u[5], u[6], u[7]);
    } else {
        const int idx = blk - BB * 32 * 4;
        const int b = idx & 7;            // XCD-affine
        const int s = (idx >> 3) * 256 + t;
        const float* sb = sxyz + (long)b * 3 * SS;
        unsigned short* gb = gt + (long)b * 2 * SS * 8;

        float px = sb[s], py = sb[SS + s], pz = sb[2 * SS + s];
        unsigned short xh = f2bf(px); unsigned short xl = f2bf(px - bf2f(xh));
        unsigned short yh = f2bf(py); unsigned short yl = f2bf(py - bf2f(yh));
        unsigned short zh = f2bf(pz); unsigned short zl = f2bf(pz - bf2f(zh));
        float pn = fmaf(px, px, fmaf(py, py, pz * pz));
        unsigned short nh = f2bf(pn); unsigned short nl = f2bf(pn - bf2f(nh));
        const unsigned ONE = 0x3F80u;
        // k0..7  = [xh, xl, xh, yh, yl, yh, zh, zl]
        uint4 t0 = make_uint4((unsigned)xh | ((unsigned)xl << 16),
                              (unsigned)xh | ((unsigned)yh << 16),
                              (unsigned)yl | ((unsigned)yh << 16),
                              (unsigned)zh | ((unsigned)zl << 16));
        // k8..15 = [zh, nh, nl, 1, 1, xl, yl, zl]
        uint4 t1 = make_uint4((unsigned)zh | ((unsigned)nh << 16),
                              (unsigned)nl | (ONE << 16),
                              ONE | ((unsigned)xl << 16),
                              (unsigned)yl | ((unsigned)zl << 16));
        *(uint4*)&gb[(long)s * 8] = t0;
        *(uint4*)&gb[((long)SS + s) * 8] = t1;
    }
}

// ---------------- Kernel A: 32x32x16-MFMA KNN + fused IDW accumulation ------
// Wave (p = query group, sh = point half): 32 queries x 1024 points in 32
// steps. Lane (qc = lane&31, h = lane>>5): supplies A row qc of tile t_h
// (k = 8h..8h+7) and B col qc (query dims k = 8h..8h+7); D gives 16 point-
// rows {(r&3)+8(r>>2)+4h} per lane. Same 13-dim split-bf16 distance, K=16
// exactly. 4 lists/query (2 sh x 2 h) -> phases 2/3 unchanged from r11.
__global__ __launch_bounds__(256, 4) void knn_kernel(
    const float* __restrict__ xyz,         // [B,3,N]
    const float* __restrict__ sxyz,        // [B,3,S]
    const unsigned short* __restrict__ gt, // [B][2][SS][8] split-bf16 tiles
    const unsigned short* __restrict__ sft,// [B][S][C] f16 features
    float* __restrict__ out)               // [B,C,N]
{
    __shared__ unsigned mbuf[QPB * MSTRIDE];          // 10.25 KB
    __shared__ unsigned pk_lds[QPB * KNN];            // 2 KB

    const int b    = blockIdx.x & 7;                  // XCD-affine batch
    const int q0   = (int)(blockIdx.x >> 3) * QPB;    // 128 q-groups per batch
    const int tid  = threadIdx.x;
    const int wave = tid >> 6;
    const int lane = tid & 63;
    const int p    = wave & 1;                        // query group (32 queries)
    const int sh   = wave >> 1;                       // point half (1024 points)
    const int qc   = lane & 31;                       // query col / A point row
    const int h    = lane >> 5;                       // k-slice (t0 / t1)

    const float* sb = sxyz + (long)b * 3 * SS;
    const float* xb = xyz + (long)b * 3 * NN;

    // ---- per-lane query B-fragment: col = qc, k = 8h..8h+7 -----------------
    const int nq = q0 + p * 32 + qc;
    const float qx = xb[nq], qy = xb[NN + nq], qz = xb[2 * NN + nq];

    bf16x8_t qf;
    {
        unsigned short xh = f2bf(qx); float xhf = bf2f(xh);
        unsigned short yh = f2bf(qy); float yhf = bf2f(yh);
        unsigned short zh = f2bf(qz); float zhf = bf2f(zh);
        unsigned short xh2 = f2bf(-2.f * xhf), xl2 = f2bf(-2.f * (qx - xhf));
        unsigned short yh2 = f2bf(-2.f * yhf), yl2 = f2bf(-2.f * (qy - yhf));
        unsigned short zh2 = f2bf(-2.f * zhf), zl2 = f2bf(-2.f * (qz - zhf));
        float qn = fmaf(qx, qx, fmaf(qy, qy, qz * qz)) + 0.0625f;  // bias keeps d>0
        unsigned short nh = f2bf(qn); unsigned short nl = f2bf(qn - bf2f(nh));
        const short ONE = (short)0x3F80;
        if (h == 0) {
            // k0..7 vs t0 = [xh, xl, xh, yh, yl, yh, zh, zl]
            qf[0] = (short)xh2; qf[1] = (short)xh2; qf[2] = (short)xl2;
            qf[3] = (short)yh2; qf[4] = (short)yh2; qf[5] = (short)yl2;
            qf[6] = (short)zh2; qf[7] = (short)zh2;
        } else {
            // k8..15 vs t1 = [zh, nh, nl, 1, 1, xl, yl, zl]
            qf[0] = (short)zl2; qf[1] = ONE; qf[2] = ONE;
            qf[3] = (short)nh;  qf[4] = (short)nl;
            qf[5] = (short)xl2; qf[6] = (short)yl2; qf[7] = (short)zl2;
        }
    }

    // ---- phase 1: 32 MFMA steps (32 points each), depth-2 prefetch ---------
    const unsigned short* ap =
        gt + (long)b * 2 * SS * 8 + (long)h * SS * 8 + ((long)sh * 1024 + qc) * 8;

    unsigned k1[TOPM];
#pragma unroll
    for (int j = 0; j < TOPM; ++j) k1[j] = 0xFFFFFFFFu;

    const f32x16_t zacc = (f32x16_t)0.f;
    const unsigned sb0 = (unsigned)(sh * 1024 + 4 * h);

    bf16x8_t a0 = *(const bf16x8_t*)ap;            // step 0
    bf16x8_t a1 = *(const bf16x8_t*)(ap + 256);    // step 1
    ap += 512;

    for (int step = 0; step < 30; step += 2) {
        f32x16_t d0 = __builtin_amdgcn_mfma_f32_32x32x16_bf16(a0, qf, zacc, 0, 0, 0);
        a0 = *(const bf16x8_t*)ap;                 // load for step+2
        ins_step16(k1, d0, sb0 + (unsigned)(step * 32));
        f32x16_t d1 = __builtin_amdgcn_mfma_f32_32x32x16_bf16(a1, qf, zacc, 0, 0, 0);
        a1 = *(const bf16x8_t*)(ap + 256);         // load for step+3
        ap += 512;
        ins_step16(k1, d1, sb0 + (unsigned)((step + 1) * 32));
    }
    {
        f32x16_t d0 = __builtin_amdgcn_mfma_f32_32x32x16_bf16(a0, qf, zacc, 0, 0, 0);
        ins_step16(k1, d0, sb0 + (unsigned)(30 * 32));
        f32x16_t d1 = __builtin_amdgcn_mfma_f32_32x32x16_bf16(a1, qf, zacc, 0, 0, 0);
        ins_step16(k1, d1, sb0 + (unsigned)(31 * 32));
    }

    {
        // list L = sh*2 + h; query row = p*32 + qc
        unsigned* m1 = &mbuf[(p * 32 + qc) * MSTRIDE + (sh * 2 + h) * TOPM];
#pragma unroll
        for (int j = 0; j < TOPM; ++j) m1[j] = k1[j];
    }
    __syncthreads();

    // ---- phase 2: u32 funnel (40 -> top-10) + f64 re-rank of 10 ------------
    if (tid < QPB) {
        const int n2 = q0 + tid;
        const unsigned* ml = &mbuf[tid * MSTRIDE];

        // cheap u32 merge of the 4 approx lists (med3 insert, 40 x 10 ops)
        unsigned f1[TOPM];
#pragma unroll
        for (int j = 0; j < TOPM; ++j) f1[j] = 0xFFFFFFFFu;
#pragma unroll 4
        for (int j = 0; j < NLIST * TOPM; ++j) ins1(f1, ml[j]);

        // exact f64 distances for the surviving 10, insert into top-8 u64
        const double dqx = (double)xb[n2], dqy = (double)xb[NN + n2], dqz = (double)xb[2 * NN + n2];
        unsigned long long top[KNN];
#pragma unroll
        for (int j = 0; j < KNN; ++j) top[j] = ~0ull;

#pragma unroll
        for (int j = 0; j < TOPM; ++j) {
            int s = f1[j] & 0x7FF;
            float px = sb[s], py = sb[SS + s], pz = sb[2 * SS + s];  // L2-hot
            double ex = (double)px - dqx;
            double ey = (double)py - dqy;
            double ez = (double)pz - dqz;
            double dd = ex * ex + ey * ey + ez * ez;
            unsigned long long c =
                (((unsigned long long)__double_as_longlong(dd)) & ~0x7FFull) | (unsigned long long)s;
#pragma unroll
            for (int jj = KNN - 1; jj >= 1; --jj)
                top[jj] = UMIN(UMAX(top[jj - 1], c), top[jj]);
            top[0] = UMIN(top[0], c);
        }

        // IDW weights (f32 math, f16-rounded weight as before)
        const float fqx = xb[n2], fqy = xb[NN + n2], fqz = xb[2 * NN + n2];
        int   id[KNN];
        float inv[KNN];
        float ssum = 0.f;
#pragma unroll
        for (int k = 0; k < KNN; ++k) {
            id[k] = (int)(top[k] & 0x7FFull);
            float px = sb[id[k]], py = sb[SS + id[k]], pz = sb[2 * SS + id[k]];
            float dx = px - fqx, dy = py - fqy, dz = pz - fqz;
            float dv = sqrtf(dx * dx + dy * dy + dz * dz);
            dv = fmaxf(dv, 1e-10f);
            inv[k] = 1.0f / dv;
            ssum += inv[k];
        }
        const float rs = 1.0f / ssum;
#pragma unroll
        for (int k = 0; k < KNN; ++k) {
            unsigned hw = (unsigned)__half_as_ushort(__float2half_rn(inv[k] * rs));
            pk_lds[tid * KNN + k] = (hw << 16) | (unsigned)id[k];
        }
    }
    __syncthreads();

    // ---- phase 3 (fused accum): thread = (query q, channel-lane cl) --------
    {
        const int q  = tid >> 2;
        const int cl = tid & 3;
        const unsigned short* sfb = sft + (long)b * SS * CC;
        float* outq = out + (long)b * CC * NN + (q0 + q);

        // hoisted decode: weights + row offsets once per thread
        float wgt[KNN];
        long  off[KNN];
#pragma unroll
        for (int k = 0; k < KNN; ++k) {
            const unsigned pk = pk_lds[q * KNN + k];          // LDS broadcast
            off[k] = (long)(pk & 0x7FF) * CC;
            wgt[k] = __half2float(__ushort_as_half((unsigned short)(pk >> 16)));
        }

#pragma unroll
        for (int cc = 0; cc < 8; ++cc) {
            const int ch = cc * 32 + cl * 8;
            float acc[8];
#pragma unroll
            for (int j = 0; j < 8; ++j) acc[j] = 0.f;

#pragma unroll
            for (int k = 0; k < KNN; ++k) {
                const float w = wgt[k];
                const uint4 F = *(const uint4*)&sfb[off[k] + ch];  // 16B = 8 ch (L2-hit)
                float2 f0 = unpack_h2(F.x), f1 = unpack_h2(F.y);
                float2 f2 = unpack_h2(F.z), f3 = unpack_h2(F.w);
                acc[0] = fmaf(w, f0.x, acc[0]);
                acc[1] = fmaf(w, f0.y, acc[1]);
                acc[2] = fmaf(w, f1.x, acc[2]);
                acc[3] = fmaf(w, f1.y, acc[3]);
                acc[4] = fmaf(w, f2.x, acc[4]);
                acc[5] = fmaf(w, f2.y, acc[5]);
                acc[6] = fmaf(w, f3.x, acc[6]);
                acc[7] = fmaf(w, f3.y, acc[7]);
            }
#pragma unroll
            for (int j = 0; j < 8; ++j)
                __builtin_nontemporal_store(acc[j], &outq[(long)(ch + j) * NN]);
        }
    }
}

extern "C" void kernel_launch(void* const* d_in, const int* in_sizes, int n_in,
                              void* d_out, int out_size, void* d_ws, size_t ws_size,
                              hipStream_t stream) {
    const float* xyz  = (const float*)d_in[0];   // [8,3,8192]
    const float* sxyz = (const float*)d_in[1];   // [8,3,2048]
    const float* sf   = (const float*)d_in[2];   // [8,256,2048]
    float* out = (float*)d_out;                  // [8,256,8192]

    unsigned short* gtile = (unsigned short*)d_ws;                        // 512 KB
    unsigned short* sft   = (unsigned short*)((char*)d_ws + 512 * 1024);  // 8 MB

    prep_kernel<<<dim3(BB * 32 * 4 + 64), dim3(256), 0, stream>>>(sf, sxyz, sft, gtile);
    knn_kernel<<<dim3(BB * NN / QPB), dim3(256), 0, stream>>>(xyz, sxyz, gtile, sft, out);
}